// Round 7
// baseline (779.552 us; speedup 1.0000x reference)
//
#include <hip/hip_runtime.h>
#include <hip/hip_bf16.h>

typedef __hip_bfloat16 bf16;
typedef __bf16 v8bf __attribute__((ext_vector_type(8)));
typedef float v4f __attribute__((ext_vector_type(4)));

#define PB 2304
#define PTOT 4608

__device__ __forceinline__ float b2f(bf16 x){ return __bfloat162float(x); }
__device__ __forceinline__ bf16 f2b(float x){ return __float2bfloat16(x); }
__device__ __forceinline__ float softplus_f(float x){
  return fmaxf(x, 0.f) + log1pf(expf(-fabsf(x)));
}
__device__ __forceinline__ float LD(const void* src, size_t i, int fl){
  return fl ? ((const float*)src)[i] : b2f(((const bf16*)src)[i]);
}

// async global->LDS DMA, 16B per lane; LDS dest is wave-uniform base + lane*16
__device__ __forceinline__ void gload_lds16(const void* g, void* l){
  __builtin_amdgcn_global_load_lds(
      (const __attribute__((address_space(1))) void*)g,
      (__attribute__((address_space(3))) void*)l, 16, 0, 0);
}

// ---------- dtype sniffer (flag=1 if f32) + ZPAD zeroing ----------
__global__ __launch_bounds__(256) void k_sniff(const unsigned* __restrict__ x, int* __restrict__ flag,
                                               float* __restrict__ zp){
  int t = threadIdx.x;
  if (t < 128) zp[t] = 0.f;
  int cnt = 0;
  for (int i = t; i < 4096; i += 256){
    unsigned e = (x[i] >> 8) & 0x7F;
    if (e >= 0x38 && e <= 0x42) cnt++;
  }
  for (int off = 32; off; off >>= 1) cnt += __shfl_down(cnt, off, 64);
  __shared__ int sc[4];
  if ((t & 63) == 0) sc[t >> 6] = cnt;
  __syncthreads();
  if (t == 0) *flag = (sc[0]+sc[1]+sc[2]+sc[3] < 2048) ? 1 : 0;
}

// ---------- merged small-tensor canonicalization to f32 + MB zeroing ----------
__global__ __launch_bounds__(256) void k_cvt_small(
    const void* s4, const void* s10, const void* s16, const void* s6, const void* s8,
    const void* s12, const void* s14, const void* s18, const void* s20,
    const void* s21, const void* s22, const void* s23, const void* s24,
    const void* s25, const void* s26,
    float* __restrict__ dst, const int* __restrict__ flag, float* __restrict__ MB){
  int i = blockIdx.x*256 + threadIdx.x;
  if (i >= 40537) return;
  if (i >= 31321){ MB[i - 31321] = 0.f; return; }
  int fl = *flag;
  const void* src; size_t off;
  if      (i < 128)   { src = s4;  off = i; }
  else if (i < 256)   { src = s10; off = i - 128; }
  else if (i < 384)   { src = s16; off = i - 256; }
  else if (i < 3456)  { src = s6;  off = i - 384; }
  else if (i < 6528)  { src = s8;  off = i - 3456; }
  else if (i < 6536)  { src = s12; off = i - 6528; }
  else if (i < 6544)  { src = s14; off = i - 6536; }
  else if (i < 6560)  { src = s18; off = i - 6544; }
  else if (i < 6576)  { src = s20; off = i - 6560; }
  else if (i < 31152) { src = s21; off = i - 6576; }
  else if (i < 31160) { src = s22; off = i - 31152; }
  else if (i < 31288) { src = s23; off = i - 31160; }
  else if (i < 31304) { src = s24; off = i - 31288; }
  else if (i < 31320) { src = s25; off = i - 31304; }
  else                { src = s26; off = i - 31320; }
  dst[i] = LD(src, off, fl);
}

// ---------- BCOL[64]: per-column biases for the small GEMMs ----------
__global__ __launch_bounds__(256) void k_bcol(const float* __restrict__ SMALLF, float* __restrict__ BCOL){
  int t = threadIdx.x;
  const float* BG1 = SMALLF + 6528; const float* BB1 = SMALLF + 6536;
  const float* BG2 = SMALLF + 6544; const float* BB2 = SMALLF + 6560;
  const float* BB0 = SMALLF + 3456; const float* W0  = SMALLF + 6576;
  if (t < 8)       BCOL[t] = BG1[t];
  else if (t < 16) BCOL[t] = BB1[t-8];
  else if (t < 32) BCOL[t] = BG2[t-16];
  else if (t < 48) BCOL[t] = BB2[t-32];
  else if (t < 64) BCOL[t] = 0.f;
  float part[8] = {0,0,0,0,0,0,0,0};
  for (int c = t; c < 3072; c += 256){
    float bb = BB0[c];
    #pragma unroll
    for (int oc = 0; oc < 8; oc++) part[oc] += bb*W0[oc*3072 + c];
  }
  __shared__ float red[4][8];
  int wv = t >> 6, lane = t & 63;
  #pragma unroll
  for (int oc = 0; oc < 8; oc++){
    float v = part[oc];
    for (int off = 32; off; off >>= 1) v += __shfl_down(v, off, 64);
    if (lane == 0) red[wv][oc] = v;
  }
  __syncthreads();
  if (t < 8) BCOL[48 + t] = red[0][t] + red[1][t] + red[2][t] + red[3][t];
}

// ---------- M_beta: coalesced rewrite. MB[oc][dyx*128+ic] = sum_n wb0[n,ic,dyx]*w0[oc,n] ----------
// Stages 8 n-rows (full 1152 width) into LDS coalesced; old version read at lane-stride 9
// (9x amplification). grid 24 [n-chunks of 128], block 256.
__global__ __launch_bounds__(256) void k_mbeta(const void* __restrict__ wb0, const int* __restrict__ flag,
                                               const float* __restrict__ w0f, float* __restrict__ MB){
  __shared__ float wl[8][1152];
  int t = threadIdx.x;
  int nb = blockIdx.x;
  int fl = *flag;
  float acc[5][8];
  #pragma unroll
  for (int jt = 0; jt < 5; jt++)
    #pragma unroll
    for (int oc = 0; oc < 8; oc++) acc[jt][oc] = 0.f;
  for (int ns = 0; ns < 16; ns++){
    int n0 = nb*128 + ns*8;
    for (int i = t; i < 9216; i += 256)
      wl[i/1152][i%1152] = LD(wb0, (size_t)(n0 + i/1152)*1152 + (i%1152), fl);
    __syncthreads();
    #pragma unroll
    for (int nl = 0; nl < 8; nl++){
      int n = n0 + nl;
      float w0v[8];
      #pragma unroll
      for (int oc = 0; oc < 8; oc++) w0v[oc] = w0f[oc*3072 + n];
      #pragma unroll
      for (int jt = 0; jt < 5; jt++){
        int j = jt*256 + t;
        float wv = (j < 1152) ? wl[nl][j] : 0.f;
        #pragma unroll
        for (int oc = 0; oc < 8; oc++) acc[jt][oc] += wv*w0v[oc];
      }
    }
    __syncthreads();
  }
  #pragma unroll
  for (int jt = 0; jt < 5; jt++){
    int jraw = jt*256 + t;
    if (jraw < 1152){
      int ic = jraw/9, dyx = jraw%9;
      int j = dyx*128 + ic;
      #pragma unroll
      for (int oc = 0; oc < 8; oc++) atomicAdd(&MB[oc*1152 + j], acc[jt][oc]);
    }
  }
}

__global__ __launch_bounds__(256) void k_wsm(const float* __restrict__ MB, bf16* __restrict__ WSMALL){
  int i = blockIdx.x*256 + threadIdx.x;
  if (i >= 9216) return;
  float v = MB[i];
  bf16 hi = f2b(v);
  WSMALL[48*1152 + i] = hi;
  WSMALL[56*1152 + i] = f2b(v - b2f(hi));
}

// ---------- merged small weight permutes: 4 tensors -> WSMALL slices, one launch ----------
__global__ __launch_bounds__(256) void k_permW4(const void* __restrict__ s11, const void* __restrict__ s13,
                                                const void* __restrict__ s17, const void* __restrict__ s19,
                                                bf16* __restrict__ WSMALL, const int* __restrict__ flag){
  int i = blockIdx.x*256 + threadIdx.x;
  if (i >= 55296) return;
  const void* src; bf16* dst; int idx;
  if      (i < 9216) { src = s11; dst = WSMALL;           idx = i; }
  else if (i < 18432){ src = s13; dst = WSMALL + 8*1152;  idx = i - 9216; }
  else if (i < 36864){ src = s17; dst = WSMALL + 16*1152; idx = i - 18432; }
  else               { src = s19; dst = WSMALL + 32*1152; idx = i - 36864; }
  int oc = idx / 1152, rr = idx % 1152;
  int dyx = rr >> 7, ic = rr & 127;
  dst[idx] = f2b(LD(src, (size_t)(oc*128 + ic)*9 + dyx, *flag));
}

// ---------- coalesced oc-major permute for WG0: (oc, ic128, 3,3) -> (oc, dyx, ic), bf16 ----------
__global__ __launch_bounds__(256) void k_permoc(const void* __restrict__ src, bf16* __restrict__ dst,
                                                const int* __restrict__ flag){
  __shared__ float lds[4608];
  int t = threadIdx.x;
  size_t base = (size_t)blockIdx.x*4608;
  int fl = *flag;
  for (int i = t; i < 4608; i += 256) lds[i] = LD(src, base + i, fl);
  __syncthreads();
  for (int i = t; i < 4608; i += 256){
    int ocl = i / 1152, r = i - ocl*1152;
    int dyx = r >> 7, ic = r & 127;
    dst[base + i] = f2b(lds[ocl*1152 + ic*9 + dyx]);
  }
}

// ---------- coalesced ws permute: (oc, ic768, 3,3) -> WSP[oc][dyx][ic] f32 ----------
__global__ __launch_bounds__(256) void k_permws(const void* __restrict__ ws0, const void* __restrict__ ws1,
                                                const void* __restrict__ ws2, const int* __restrict__ flag,
                                                float* __restrict__ WSP){
  __shared__ float lds[6912];
  int t = threadIdx.x;
  int oc = blockIdx.x;
  int l = oc >> 7, ocl = oc & 127;
  const void* src = l == 0 ? ws0 : (l == 1 ? ws1 : ws2);
  int fl = *flag;
  for (int i = t; i < 6912; i += 256) lds[i] = LD(src, (size_t)ocl*6912 + i, fl);
  __syncthreads();
  float* o = WSP + (size_t)oc*6912;
  for (int i = t; i < 6912; i += 256){
    int dyx = i / 768, ic = i - dyx*768;
    o[i] = lds[ic*9 + dyx];
  }
}

// ---------- segment means over 24x24 downsampled segmap ----------
__global__ __launch_bounds__(256) void k_seg_means(const void* __restrict__ f_sem, const int* __restrict__ flag,
                                                   const int* __restrict__ segmap,
                                                   float* __restrict__ means){
  int s = blockIdx.x, b = blockIdx.y, t = threadIdx.x;
  int fl = *flag;
  __shared__ int sid[576];
  for (int i = t; i < 576; i += 256){
    int y = i / 24, x = i % 24;
    int v = segmap[b*336*336 + (y*14)*336 + x*14];
    sid[i] = min(max(v, 0), 63);
  }
  __syncthreads();
  float a0=0.f, a1=0.f, a2=0.f; int cnt = 0;
  for (int i = 0; i < 576; i++){
    if (sid[i] == s){
      cnt++;
      a0 += LD(f_sem, (size_t)(b*768 + t      )*576 + i, fl);
      a1 += LD(f_sem, (size_t)(b*768 + t + 256)*576 + i, fl);
      a2 += LD(f_sem, (size_t)(b*768 + t + 512)*576 + i, fl);
    }
  }
  float inv = cnt > 0 ? 1.f/(float)cnt : 0.f;
  float* o = means + (size_t)(b*64 + s)*768;
  o[t] = a0*inv; o[t+256] = a1*inv; o[t+512] = a2*inv;
}

// ---------- TT[b][oc][dyx][s] = sum_ic WSP[oc][dyx][ic] * means[b][s][ic] ----------
__global__ __launch_bounds__(256) void k_tt(const float* __restrict__ WSP,
    const float* __restrict__ means, bf16* __restrict__ WTT){
  int bx = blockIdx.x;
  int dyx = bx / 24, ocb = bx % 24;
  int b = blockIdx.y, t = threadIdx.x;
  int ocg0 = ocb*16;
  __shared__ float wl[16][768];
  for (int ol = 0; ol < 16; ol++)
    for (int ic = t; ic < 768; ic += 256)
      wl[ol][ic] = WSP[(size_t)(ocg0 + ol)*6912 + (size_t)dyx*768 + ic];
  __syncthreads();
  int s = t & 63, og = t >> 6;
  const float* mr = means + ((size_t)b*64 + s)*768;
  float acc[4] = {0.f, 0.f, 0.f, 0.f};
  for (int ic = 0; ic < 768; ic += 4){
    float4 m = *reinterpret_cast<const float4*>(mr + ic);
    #pragma unroll
    for (int k = 0; k < 4; k++){
      const float* w = &wl[og + k*4][ic];
      acc[k] += m.x*w[0] + m.y*w[1] + m.z*w[2] + m.w*w[3];
    }
  }
  #pragma unroll
  for (int k = 0; k < 4; k++){
    bf16 h = f2b(acc[k]);
    size_t base = ((size_t)(b*384 + ocg0 + og + k*4))*1152 + (size_t)dyx*128 + s;
    WTT[base] = h;
    WTT[base + 64] = h;
  }
}

// ---------- per-pixel segment weights (antialiased bilinear 336->48), bf16 hi/lo out ----------
__global__ __launch_bounds__(192) void k_A(const int* __restrict__ segmap, bf16* __restrict__ AHL){
  int blk = blockIdx.x;
  int b = blk / PB, rem = blk % PB, yo = rem / 48, xo = rem % 48;
  __shared__ float accs[64];
  int t = threadIdx.x;
  if (t < 64) accs[t] = 0.f;
  __syncthreads();
  if (t < 169){
    int ty = t / 13, tx = t % 13;
    int jy = 7*yo - 3 + ty, jx = 7*xo - 3 + tx;
    if (jy >= 0 && jy < 336 && jx >= 0 && jx < 336){
      int wy = 7 - abs(ty - 6), wx = 7 - abs(tx - 6);
      int sv = segmap[b*336*336 + jy*336 + jx];
      sv = min(max(sv, 0), 63);
      atomicAdd(&accs[sv], (float)(wy*wx));
    }
  }
  int sumy = 0, sumx = 0;
  for (int k = 0; k < 13; k++){
    int jy = 7*yo - 3 + k; if (jy >= 0 && jy < 336) sumy += 7 - abs(k - 6);
    int jx = 7*xo - 3 + k; if (jx >= 0 && jx < 336) sumx += 7 - abs(k - 6);
  }
  __syncthreads();
  if (t < 64){
    float v = accs[t] / (float)(sumy*sumx);
    bf16 hi = f2b(v);
    AHL[(size_t)blk*128 + t] = hi;
    AHL[(size_t)blk*128 + 64 + t] = f2b(v - b2f(hi));
  }
}

// ---------- LN stats over x_main ----------
__global__ __launch_bounds__(256) void k_ln_partial(const void* __restrict__ x, const int* __restrict__ flag,
                                                    float2* __restrict__ part){
  int b = blockIdx.y, blk = blockIdx.x, t = threadIdx.x;
  int fl = *flag;
  size_t base = (size_t)b*7077888 + (size_t)blk*55296;
  float s = 0.f, sq = 0.f;
  for (int i = 0; i < 216; i++){
    float v = LD(x, base + t + i*256, fl);
    s += v; sq += v*v;
  }
  for (int off = 32; off; off >>= 1){ s += __shfl_down(s, off, 64); sq += __shfl_down(sq, off, 64); }
  __shared__ float ls[4], lq[4];
  int w = t >> 6, lane = t & 63;
  if (lane == 0){ ls[w] = s; lq[w] = sq; }
  __syncthreads();
  if (t == 0) part[b*128 + blk] = make_float2(ls[0]+ls[1]+ls[2]+ls[3], lq[0]+lq[1]+lq[2]+lq[3]);
}

__global__ void k_ln_final(const float2* __restrict__ part, float* __restrict__ stats){
  int b = blockIdx.x, t = threadIdx.x;
  float2 v = part[b*128 + t];
  float s = v.x, sq = v.y;
  for (int off = 32; off; off >>= 1){ s += __shfl_down(s, off, 64); sq += __shfl_down(sq, off, 64); }
  __shared__ float ls[2], lq[2];
  if ((t & 63) == 0){ ls[t>>6] = s; lq[t>>6] = sq; }
  __syncthreads();
  if (t == 0){
    s = ls[0]+ls[1]; sq = lq[0]+lq[1];
    const float N = 7077888.f;
    float mean = s/N; float var = sq/N - mean*mean; var = fmaxf(var, 0.f);
    stats[b*2] = mean; stats[b*2+1] = rsqrtf(var + 1e-12f);
  }
}

// ---------- softplus-in-place + LN stats (fused) ----------
__global__ __launch_bounds__(256) void k_spln(float* __restrict__ z, int cnt, float* __restrict__ stats){
  int b = blockIdx.x, t = threadIdx.x;
  float* p = z + (size_t)b*cnt;
  float s = 0.f, sq = 0.f;
  for (int i = t; i < cnt; i += 256){
    float v = softplus_f(p[i]);
    p[i] = v;
    s += v; sq += v*v;
  }
  for (int off = 32; off; off >>= 1){ s += __shfl_down(s, off, 64); sq += __shfl_down(sq, off, 64); }
  __shared__ float ls[4], lq[4];
  int w = t >> 6, lane = t & 63;
  if (lane == 0){ ls[w] = s; lq[w] = sq; }
  __syncthreads();
  if (t == 0){
    s = ls[0]+ls[1]+ls[2]+ls[3]; sq = lq[0]+lq[1]+lq[2]+lq[3];
    float mean = s/(float)cnt; float var = sq/(float)cnt - mean*mean; var = fmaxf(var, 0.f);
    stats[b*2] = mean; stats[b*2+1] = rsqrtf(var + 1e-12f);
  }
}

__global__ __launch_bounds__(256) void k_ln_small(const float* __restrict__ z, int cnt, float* __restrict__ stats){
  int b = blockIdx.x, t = threadIdx.x;
  const float* p = z + (size_t)b*cnt;
  float s = 0.f, sq = 0.f;
  for (int i = t; i < cnt; i += 256){ float v = p[i]; s += v; sq += v*v; }
  for (int off = 32; off; off >>= 1){ s += __shfl_down(s, off, 64); sq += __shfl_down(sq, off, 64); }
  __shared__ float ls[4], lq[4];
  int w = t >> 6, lane = t & 63;
  if (lane == 0){ ls[w] = s; lq[w] = sq; }
  __syncthreads();
  if (t == 0){
    s = ls[0]+ls[1]+ls[2]+ls[3]; sq = lq[0]+lq[1]+lq[2]+lq[3];
    float mean = s/(float)cnt; float var = sq/(float)cnt - mean*mean; var = fmaxf(var, 0.f);
    stats[b*2] = mean; stats[b*2+1] = rsqrtf(var + 1e-12f);
  }
}

// ---------- shared MFMA GEMM body (BK=64, 64x64 tile, 2-barrier structure) ----------
template<bool RELU, typename OT>
__device__ __forceinline__ void gemm_body(
    const bf16* __restrict__ Asrc, int AS, int acol, int ICW,
    const bf16* __restrict__ W, int K, size_t wbstride,
    const float* __restrict__ bp0, const float* __restrict__ bp1, const float* __restrict__ bp2, int seg,
    OT* __restrict__ out, int N, int ncb, int ldo, const bf16* __restrict__ zpad,
    int m0, int n0, bf16 (*Al)[64], bf16 (*Bl)[64])
{
  int t = threadIdx.x;
  int wv = t >> 6, lane = t & 63;
  int lr8 = lane >> 3, sseg = (lane & 7) ^ lr8;   // source 16B-seg (swizzled)
  int b = m0 >= PB ? 1 : 0;

  int ya[2], xa[2]; bool bv[2]; const bf16* wb[2];
  #pragma unroll
  for (int i = 0; i < 2; i++){
    int sp = (m0 - b*PB) + wv*16 + i*8 + lr8;
    ya[i] = sp / 48; xa[i] = sp % 48;
    int nrow = ncb + n0 + wv*16 + i*8 + lr8;
    bv[i] = nrow < N;
    wb[i] = W + (size_t)b*wbstride + (size_t)nrow*K + sseg*8;
  }

  int wm = (wv >> 1)*32, wn = (wv & 1)*32;
  int lrow = lane & 15, quad = lane >> 4;
  int sx = lrow & 7;
  int o0 = ((quad    ) ^ sx)*8;
  int o1 = ((quad + 4) ^ sx)*8;

  v4f acc00 = {0,0,0,0}, acc01 = {0,0,0,0}, acc10 = {0,0,0,0}, acc11 = {0,0,0,0};

  int dyx = 0, ic0 = 0;
  int ktn = K / 64;
  for (int kt = 0; kt < ktn; kt++){
    int dy = dyx/3 - 1, dx = dyx%3 - 1;
    #pragma unroll
    for (int i = 0; i < 2; i++){
      int ys = ya[i] + dy, xs = xa[i] + dx;
      const bf16* ga = (ys >= 0 && ys < 48 && xs >= 0 && xs < 48)
        ? Asrc + (size_t)(b*PB + ys*48 + xs)*AS + acol + ic0 + sseg*8 : zpad;
      gload_lds16(ga, &Al[wv*16 + i*8][0]);
      const bf16* gb = bv[i] ? wb[i] + kt*64 : zpad;
      gload_lds16(gb, &Bl[wv*16 + i*8][0]);
    }
    asm volatile("s_waitcnt vmcnt(0)" ::: "memory");
    __syncthreads();
    v8bf a00 = *reinterpret_cast<const v8bf*>(&Al[wm      + lrow][o0]);
    v8bf a10 = *reinterpret_cast<const v8bf*>(&Al[wm + 16 + lrow][o0]);
    v8bf a01 = *reinterpret_cast<const v8bf*>(&Al[wm      + lrow][o1]);
    v8bf a11 = *reinterpret_cast<const v8bf*>(&Al[wm + 16 + lrow][o1]);
    v8bf b00 = *reinterpret_cast<const v8bf*>(&Bl[wn      + lrow][o0]);
    v8bf b10 = *reinterpret_cast<const v8bf*>(&Bl[wn + 16 + lrow][o0]);
    v8bf b01 = *reinterpret_cast<const v8bf*>(&Bl[wn      + lrow][o1]);
    v8bf b11 = *reinterpret_cast<const v8bf*>(&Bl[wn + 16 + lrow][o1]);
    acc00 = __builtin_amdgcn_mfma_f32_16x16x32_bf16(a00, b00, acc00, 0, 0, 0);
    acc00 = __builtin_amdgcn_mfma_f32_16x16x32_bf16(a01, b01, acc00, 0, 0, 0);
    acc01 = __builtin_amdgcn_mfma_f32_16x16x32_bf16(a00, b10, acc01, 0, 0, 0);
    acc01 = __builtin_amdgcn_mfma_f32_16x16x32_bf16(a01, b11, acc01, 0, 0, 0);
    acc10 = __builtin_amdgcn_mfma_f32_16x16x32_bf16(a10, b00, acc10, 0, 0, 0);
    acc10 = __builtin_amdgcn_mfma_f32_16x16x32_bf16(a11, b01, acc10, 0, 0, 0);
    acc11 = __builtin_amdgcn_mfma_f32_16x16x32_bf16(a10, b10, acc11, 0, 0, 0);
    acc11 = __builtin_amdgcn_mfma_f32_16x16x32_bf16(a11, b11, acc11, 0, 0, 0);
    __syncthreads();
    ic0 += 64; if (ic0 == ICW){ ic0 = 0; dyx++; }
  }

  auto store_tile = [&](v4f a, int mi, int ni){
    int gcol = ncb + n0 + wn + ni*16 + lrow;
    if (gcol >= N) return;
    int sel = gcol / seg; sel = sel > 2 ? 2 : sel;
    const float* bp = sel == 0 ? bp0 : (sel == 1 ? bp1 : bp2);
    float bias = bp[gcol - sel*seg];
    int rowb = m0 + wm + mi*16 + quad*4;
    #pragma unroll
    for (int rg = 0; rg < 4; rg++){
      float v = a[rg] + bias;
      if (RELU) v = fmaxf(v, 0.f);
      if constexpr (sizeof(OT) == 2) out[(size_t)(rowb+rg)*ldo + (gcol - ncb)] = f2b(v);
      else                           out[(size_t)(rowb+rg)*ldo + (gcol - ncb)] = (OT)v;
    }
  };
  store_tile(acc00, 0, 0); store_tile(acc01, 0, 1);
  store_tile(acc10, 1, 0); store_tile(acc11, 1, 1);
}

template<bool RELU, typename OT>
__global__ __launch_bounds__(256) void k_gemm(
    const bf16* __restrict__ Asrc, int AS, int acol, int ICW,
    const bf16* __restrict__ W, int K, size_t wbstride,
    const float* __restrict__ bp0, const float* __restrict__ bp1, const float* __restrict__ bp2, int seg,
    OT* __restrict__ out, int N, int ncb, int ldo, const bf16* __restrict__ zpad)
{
  __shared__ __align__(16) bf16 Al[64][64];
  __shared__ __align__(16) bf16 Bl[64][64];
  gemm_body<RELU, OT>(Asrc, AS, acol, ICW, W, K, wbstride, bp0, bp1, bp2, seg,
                      out, N, ncb, ldo, zpad, blockIdx.x*64, blockIdx.y*64, Al, Bl);
}

// merged 3 small GEMMs: blockIdx.y selects {gamma1, beta1+gamma2, beta2+z0beta} config
__global__ __launch_bounds__(256) void k_gsmall(
    const bf16* __restrict__ HS, const bf16* __restrict__ WSMALL, const float* __restrict__ BCOL,
    float* __restrict__ GBS, const bf16* __restrict__ zpad)
{
  __shared__ __align__(16) bf16 Al[64][64];
  __shared__ __align__(16) bf16 Bl[64][64];
  int y = blockIdx.y;
  int acol = y == 0 ? 128 : (y == 1 ? 256 : 0);
  const bf16* W = WSMALL + (y == 0 ? 0 : (y == 1 ? 16*1152 : 48*1152));
  const float* bp = BCOL + (y == 0 ? 0 : (y == 1 ? 16 : 48));
  float* out = GBS + (y == 0 ? 0 : (y == 1 ? 16 : 48));
  int N = y == 1 ? 32 : 16;
  gemm_body<false, float>(HS, 384, acol, 128, W, 1152, 0, bp, bp, bp, 9999,
                          out, N, 0, 64, zpad, blockIdx.x*64, 0, Al, Bl);
}

// ---------- pure gamma GEMM: GAMMA[p][c] = im2col(HS)*WG0^T + bg0 ----------
__global__ __launch_bounds__(256, 4) void k_gg(
    const bf16* __restrict__ HS, const bf16* __restrict__ WG0, const float* __restrict__ BG0,
    bf16* __restrict__ GAMMA, const bf16* __restrict__ zpad)
{
  __shared__ __align__(16) bf16 Al[128][64];
  __shared__ __align__(16) bf16 Bl[128][64];
  int t = threadIdx.x;
  int m0 = blockIdx.x*128, n0 = blockIdx.y*128;
  int b = m0 >= PB ? 1 : 0;
  int wv = t >> 6, lane = t & 63;
  int lr8 = lane >> 3, sseg = (lane & 7) ^ lr8;
  int spbase = m0 - b*PB;

  int ya[4], xa[4];
  #pragma unroll
  for (int i = 0; i < 4; i++){
    int sp = spbase + wv*32 + i*8 + lr8;
    ya[i] = sp / 48; xa[i] = sp % 48;
  }
  const bf16* wgb = WG0 + (size_t)(n0 + wv*32 + lr8)*1152 + sseg*8;

  int wm = wv*32, lrow = lane & 15, quad = lane >> 4;
  int sx = lrow & 7;

  v4f acc[2][8];
  #pragma unroll
  for (int mi = 0; mi < 2; mi++)
    #pragma unroll
    for (int ni = 0; ni < 8; ni++) acc[mi][ni] = (v4f){0,0,0,0};

  for (int kt = 0; kt < 18; kt++){
    int dyx = kt >> 1, icr = (kt & 1) << 6;
    int dy = dyx/3 - 1, dx = dyx%3 - 1;
    #pragma unroll
    for (int i = 0; i < 4; i++){
      int ys = ya[i] + dy, xs = xa[i] + dx;
      const bf16* ga = (ys >= 0 && ys < 48 && xs >= 0 && xs < 48)
        ? HS + (size_t)(b*PB + ys*48 + xs)*384 + icr + sseg*8 : zpad;
      gload_lds16(ga, &Al[wv*32 + i*8][0]);
      gload_lds16(wgb + (size_t)(i*8)*1152 + dyx*128 + icr, &Bl[wv*32 + i*8][0]);
    }
    asm volatile("s_waitcnt vmcnt(0)" ::: "memory");
    __syncthreads();
    #pragma unroll
    for (int kh = 0; kh < 2; kh++){
      int oa = ((kh*4 + quad) ^ sx)*8;
      v8bf a0 = *reinterpret_cast<const v8bf*>(&Al[wm      + lrow][oa]);
      v8bf a1 = *reinterpret_cast<const v8bf*>(&Al[wm + 16 + lrow][oa]);
      #pragma unroll
      for (int ni = 0; ni < 8; ni++){
        v8bf bn = *reinterpret_cast<const v8bf*>(&Bl[ni*16 + lrow][oa]);
        acc[0][ni] = __builtin_amdgcn_mfma_f32_16x16x32_bf16(a0, bn, acc[0][ni], 0, 0, 0);
        acc[1][ni] = __builtin_amdgcn_mfma_f32_16x16x32_bf16(a1, bn, acc[1][ni], 0, 0, 0);
      }
    }
    __syncthreads();
  }

  #pragma unroll
  for (int mi = 0; mi < 2; mi++){
    int pr = m0 + wm + mi*16 + quad*4;
    #pragma unroll
    for (int ni = 0; ni < 8; ni++){
      int gc = n0 + ni*16 + lrow;
      float bg = BG0[gc];
      #pragma unroll
      for (int rg = 0; rg < 4; rg++)
        GAMMA[(size_t)(pr + rg)*3072 + gc] = f2b(acc[mi][ni][rg] + bg);
    }
  }
}

// ---------- z0 contraction v2: z0[p,oc] += sum_c xn[p,c]*(1+gamma[p,c])*w0[oc,c] ----------
// 128px x 128c blocks, grid (36,24)=864 (was (72,8)=576 @ Occ 13% -> latency-bound).
// 2 px/lane vectorized x loads; gamma LDS-transposed (odd-stride pad); red padded [..][9]
// to fix the 32-way reduction-write conflict of the old [..][8] layout.
__global__ __launch_bounds__(256) void k_zc(
    const void* __restrict__ x, const bf16* __restrict__ GAMMA, const int* __restrict__ flag,
    const float* __restrict__ stats, const float* __restrict__ w0f, float* __restrict__ z0)
{
  __shared__ bf16 gmT[64][130];     // [c][px] 64c x 128px; word-stride 65 (odd) -> conflict-free
  __shared__ float w0l[8][128];
  __shared__ float red[4][128][9];  // pad 9 -> 4-way max on writes
  int t = threadIdx.x;
  int p0 = blockIdx.x*128, cb = blockIdx.y;
  int b = p0 / PB;
  int spbase = p0 - b*PB;
  int fl = *flag;
  float mean = stats[b*2], rstd = stats[b*2+1];
  int lane = t & 63, cg = t >> 6;
  int c0b = cb*128;

  for (int i = t; i < 1024; i += 256) w0l[i >> 7][i & 127] = w0f[(size_t)(i >> 7)*3072 + c0b + (i & 127)];

  float acc0[8], acc1[8];
  #pragma unroll
  for (int oc = 0; oc < 8; oc++){ acc0[oc] = 0.f; acc1[oc] = 0.f; }

  for (int ct = 0; ct < 2; ct++){
    int c0 = c0b + ct*64;
    {
      int cl = t & 63, pr = t >> 6;
      #pragma unroll
      for (int k = 0; k < 32; k++){
        int p = pr + k*4;
        gmT[cl][p] = GAMMA[(size_t)(p0 + p)*3072 + c0 + cl];
      }
    }
    __syncthreads();
    #pragma unroll
    for (int ci = 0; ci < 16; ci++){
      int c = cg*16 + ci;
      float xv0, xv1;
      if (fl){
        const float* xp = (const float*)x + ((size_t)(b*3072 + c0 + c))*2304 + spbase + lane*2;
        float2 v = *reinterpret_cast<const float2*>(xp);
        xv0 = v.x; xv1 = v.y;
      } else {
        const bf16* xp = (const bf16*)x + ((size_t)(b*3072 + c0 + c))*2304 + spbase + lane*2;
        xv0 = b2f(xp[0]); xv1 = b2f(xp[1]);
      }
      float t0 = (xv0 - mean)*rstd*(1.f + b2f(gmT[c][lane*2]));
      float t1 = (xv1 - mean)*rstd*(1.f + b2f(gmT[c][lane*2 + 1]));
      #pragma unroll
      for (int oc = 0; oc < 8; oc++){
        float wv = w0l[oc][ct*64 + c];
        acc0[oc] += t0*wv; acc1[oc] += t1*wv;
      }
    }
    __syncthreads();
  }
  #pragma unroll
  for (int oc = 0; oc < 8; oc++){
    red[cg][lane*2    ][oc] = acc0[oc];
    red[cg][lane*2 + 1][oc] = acc1[oc];
  }
  __syncthreads();
  #pragma unroll
  for (int j = 0; j < 4; j++){
    int idx = t + j*256;          // 1024 = 128 px * 8 oc
    int p2 = idx >> 3, o2 = idx & 7;
    float s = red[0][p2][o2] + red[1][p2][o2] + red[2][p2][o2] + red[3][p2][o2];
    atomicAdd(&z0[(size_t)(p0 + p2)*8 + o2], s);
  }
}

// ---------- z0 init: bias0 + beta-contraction (GBS cols 48..55 hi + 56..63 lo) ----------
__global__ __launch_bounds__(256) void k_z0init(const float* __restrict__ b0f, const float* __restrict__ GBS,
                                                float* __restrict__ z0){
  int i = blockIdx.x*256 + threadIdx.x;
  if (i >= 36864) return;
  int p = i >> 3, oc = i & 7;
  z0[i] = b0f[oc] + GBS[(size_t)p*64 + 48 + oc] + GBS[(size_t)p*64 + 56 + oc];
}

__global__ __launch_bounds__(256) void k_F1(const float* __restrict__ z0, const float* __restrict__ GBS,
    const float* __restrict__ stats, const float* __restrict__ w1f, const float* __restrict__ b1f,
    float* __restrict__ z1){
  int p = blockIdx.x*256 + threadIdx.x;
  if (p >= PTOT) return;
  int b = p / PB;
  float mean = stats[b*2], rstd = stats[b*2+1];
  const float* zr = z0 + (size_t)p*8;
  const float* gr = GBS + (size_t)p*64;
  float yv[8];
  #pragma unroll
  for (int c = 0; c < 8; c++) yv[c] = (zr[c] - mean)*rstd*(1.f + gr[c]) + gr[8 + c];
  #pragma unroll
  for (int oc = 0; oc < 16; oc++){
    float s = b1f[oc];
    #pragma unroll
    for (int c = 0; c < 8; c++) s += yv[c]*w1f[oc*8 + c];
    z1[(size_t)p*16 + oc] = softplus_f(s);
  }
}

__global__ __launch_bounds__(256) void k_F2(const float* __restrict__ z1, const float* __restrict__ GBS,
    const float* __restrict__ stats, const float* __restrict__ w2f, const float* __restrict__ b2f,
    void* __restrict__ outp, const int* __restrict__ flag){
  int p = blockIdx.x*256 + threadIdx.x;
  if (p >= PTOT) return;
  int b = p / PB;
  float mean = stats[b*2], rstd = stats[b*2+1];
  const float* zr = z1 + (size_t)p*16;
  const float* gr = GBS + (size_t)p*64 + 16;
  float s = b2f[0];
  #pragma unroll
  for (int c = 0; c < 16; c++){
    float yv = (zr[c] - mean)*rstd*(1.f + gr[c]) + gr[16 + c];
    s += yv*w2f[c];
  }
  float r = softplus_f(s);
  if (*flag) ((float*)outp)[p] = r;
  else       ((bf16*)outp)[p] = f2b(r);
}

extern "C" void kernel_launch(void* const* d_in, const int* in_sizes, int n_in,
                              void* d_out, int out_size, void* d_ws, size_t ws_size,
                              hipStream_t stream){
  const void* x_main = d_in[0];
  const void* f_sem  = d_in[1];
  const int*  segmap = (const int*)d_in[2];

  char* ws = (char*)d_ws;
  size_t o = 0;
  auto alloc = [&](size_t bytes){ size_t r = o; o = (o + bytes + 255) & ~(size_t)255; return r; };
  float* MEANS = (float*)(ws + alloc(98304u*4));
  bf16*  AHL   = (bf16*) (ws + alloc(589824u*2));    // PTOT*128 hi/lo A weights
  bf16*  WTT   = (bf16*) (ws + alloc(884736u*2));    // 2*384*1152 folded conv weights
  bf16*  WG0   = (bf16*) (ws + alloc(3538944u*2));
  bf16*  WSMALL= (bf16*) (ws + alloc(73728u*2));
  bf16*  HS    = (bf16*) (ws + alloc(1769472u*2));
  float* WSP   = (float*)(ws + alloc(2654208u*4));   // 384*6912 permuted ws (f32)
  bf16*  GAMMA = (bf16*) (ws + alloc(14155776u*2));  // 4608*3072 gamma (layer 0)
  float* GBS   = (float*)(ws + alloc(294912u*4));
  float* Z0    = (float*)(ws + alloc(36864u*4));
  float* Z1    = (float*)(ws + alloc(73728u*4));
  float2* LNP  = (float2*)(ws + alloc(256u*8));
  float* STATS = (float*)(ws + alloc(16u*4));
  int*   FLAG  = (int*)  (ws + alloc(64u));
  float* SMALLF= (float*)(ws + alloc(31321u*4));
  float* MB    = (float*)(ws + alloc(9216u*4));
  float* BCOL  = (float*)(ws + alloc(64u*4));
  bf16*  ZPAD  = (bf16*) (ws + alloc(512u));

  float *BS0=SMALLF+0, *BS1=SMALLF+128, *BS2=SMALLF+256;
  float *BG0=SMALLF+384;
  float *W0=SMALLF+6576, *B0=SMALLF+31152;
  float *W1=SMALLF+31160, *B1=SMALLF+31288;
  float *W2=SMALLF+31304, *B2=SMALLF+31320;

  k_sniff<<<1, 256, 0, stream>>>((const unsigned*)x_main, FLAG, (float*)ZPAD);
  k_cvt_small<<<159, 256, 0, stream>>>(d_in[4], d_in[10], d_in[16], d_in[6], d_in[8],
      d_in[12], d_in[14], d_in[18], d_in[20], d_in[21], d_in[22], d_in[23], d_in[24],
      d_in[25], d_in[26], SMALLF, FLAG, MB);
  k_bcol<<<1, 256, 0, stream>>>(SMALLF, BCOL);
  k_mbeta<<<24, 256, 0, stream>>>(d_in[7], FLAG, W0, MB);
  k_wsm<<<36, 256, 0, stream>>>(MB, WSMALL);

  k_permoc<<<768, 256, 0, stream>>>(d_in[5], WG0, FLAG);          // coalesced WG0 permute
  k_permws<<<384, 256, 0, stream>>>(d_in[3], d_in[9], d_in[15], FLAG, WSP);
  k_permW4<<<216, 256, 0, stream>>>(d_in[11], d_in[13], d_in[17], d_in[19], WSMALL, FLAG);

  k_ln_partial<<<dim3(128,2), 256, 0, stream>>>(x_main, FLAG, LNP);
  k_ln_final<<<2, 128, 0, stream>>>(LNP, STATS);
  k_seg_means<<<dim3(64,2), 256, 0, stream>>>(f_sem, FLAG, segmap, MEANS);
  k_tt<<<dim3(216,2), 256, 0, stream>>>(WSP, MEANS, WTT);
  k_A<<<PTOT, 192, 0, stream>>>(segmap, AHL);

  // G1: h = relu(conv3x3(sem, ws_l)) for all 3 layers -> HS (4608,384), folded-weight K=1152
  k_gemm<true, bf16><<<dim3(72,6), 256, 0, stream>>>(AHL, 128, 0, 128, WTT, 1152, (size_t)384*1152,
      BS0, BS1, BS2, 128, HS, 384, 0, 384, ZPAD);
  // merged small GEMMs (gamma1/beta1/gamma2/beta2/z0beta)
  k_gsmall<<<dim3(72,3), 256, 0, stream>>>(HS, WSMALL, BCOL, GBS, ZPAD);

  // layer-0 split: gamma GEMM -> GAMMA, then streaming z0 contraction
  k_z0init<<<144, 256, 0, stream>>>(B0, GBS, Z0);
  k_gg<<<dim3(36,24), 256, 0, stream>>>(HS, WG0, BG0, GAMMA, ZPAD);
  k_zc<<<dim3(36,24), 256, 0, stream>>>(x_main, GAMMA, FLAG, STATS, W0, Z0);
  k_spln<<<2, 256, 0, stream>>>(Z0, 18432, STATS + 4);

  k_F1<<<18, 256, 0, stream>>>(Z0, GBS, STATS + 4, W1, B1, Z1);
  k_ln_small<<<2, 256, 0, stream>>>(Z1, 36864, STATS + 8);
  k_F2<<<18, 256, 0, stream>>>(Z1, GBS, STATS + 8, W2, B2, d_out, FLAG);
}

// Round 8
// 546.043 us; speedup vs baseline: 1.4276x; 1.4276x over previous
//
#include <hip/hip_runtime.h>
#include <hip/hip_bf16.h>

typedef __hip_bfloat16 bf16;
typedef __bf16 v8bf __attribute__((ext_vector_type(8)));
typedef float v4f __attribute__((ext_vector_type(4)));

#define PB 2304
#define PTOT 4608

__device__ __forceinline__ float b2f(bf16 x){ return __bfloat162float(x); }
__device__ __forceinline__ bf16 f2b(float x){ return __float2bfloat16(x); }
__device__ __forceinline__ float softplus_f(float x){
  return fmaxf(x, 0.f) + log1pf(expf(-fabsf(x)));
}
__device__ __forceinline__ float LD(const void* src, size_t i, int fl){
  return fl ? ((const float*)src)[i] : b2f(((const bf16*)src)[i]);
}

// async global->LDS DMA, 16B per lane; LDS dest is wave-uniform base + lane*16
__device__ __forceinline__ void gload_lds16(const void* g, void* l){
  __builtin_amdgcn_global_load_lds(
      (const __attribute__((address_space(1))) void*)g,
      (__attribute__((address_space(3))) void*)l, 16, 0, 0);
}

// ---------- dtype sniffer (flag=1 if f32) + ZPAD zeroing ----------
__global__ __launch_bounds__(256) void k_sniff(const unsigned* __restrict__ x, int* __restrict__ flag,
                                               float* __restrict__ zp){
  int t = threadIdx.x;
  if (t < 128) zp[t] = 0.f;
  int cnt = 0;
  for (int i = t; i < 4096; i += 256){
    unsigned e = (x[i] >> 8) & 0x7F;
    if (e >= 0x38 && e <= 0x42) cnt++;
  }
  for (int off = 32; off; off >>= 1) cnt += __shfl_down(cnt, off, 64);
  __shared__ int sc[4];
  if ((t & 63) == 0) sc[t >> 6] = cnt;
  __syncthreads();
  if (t == 0) *flag = (sc[0]+sc[1]+sc[2]+sc[3] < 2048) ? 1 : 0;
}

// ---------- merged small-tensor canonicalization to f32 + MB zeroing ----------
__global__ __launch_bounds__(256) void k_cvt_small(
    const void* s4, const void* s10, const void* s16, const void* s6, const void* s8,
    const void* s12, const void* s14, const void* s18, const void* s20,
    const void* s21, const void* s22, const void* s23, const void* s24,
    const void* s25, const void* s26,
    float* __restrict__ dst, const int* __restrict__ flag, float* __restrict__ MB){
  int i = blockIdx.x*256 + threadIdx.x;
  if (i >= 40537) return;
  if (i >= 31321){ MB[i - 31321] = 0.f; return; }
  int fl = *flag;
  const void* src; size_t off;
  if      (i < 128)   { src = s4;  off = i; }
  else if (i < 256)   { src = s10; off = i - 128; }
  else if (i < 384)   { src = s16; off = i - 256; }
  else if (i < 3456)  { src = s6;  off = i - 384; }
  else if (i < 6528)  { src = s8;  off = i - 3456; }
  else if (i < 6536)  { src = s12; off = i - 6528; }
  else if (i < 6544)  { src = s14; off = i - 6536; }
  else if (i < 6560)  { src = s18; off = i - 6544; }
  else if (i < 6576)  { src = s20; off = i - 6560; }
  else if (i < 31152) { src = s21; off = i - 6576; }
  else if (i < 31160) { src = s22; off = i - 31152; }
  else if (i < 31288) { src = s23; off = i - 31160; }
  else if (i < 31304) { src = s24; off = i - 31288; }
  else if (i < 31320) { src = s25; off = i - 31304; }
  else                { src = s26; off = i - 31320; }
  dst[i] = LD(src, off, fl);
}

// ---------- BCOL[64]: per-column biases for the small GEMMs ----------
__global__ __launch_bounds__(256) void k_bcol(const float* __restrict__ SMALLF, float* __restrict__ BCOL){
  int t = threadIdx.x;
  const float* BG1 = SMALLF + 6528; const float* BB1 = SMALLF + 6536;
  const float* BG2 = SMALLF + 6544; const float* BB2 = SMALLF + 6560;
  const float* BB0 = SMALLF + 3456; const float* W0  = SMALLF + 6576;
  if (t < 8)       BCOL[t] = BG1[t];
  else if (t < 16) BCOL[t] = BB1[t-8];
  else if (t < 32) BCOL[t] = BG2[t-16];
  else if (t < 48) BCOL[t] = BB2[t-32];
  else if (t < 64) BCOL[t] = 0.f;
  float part[8] = {0,0,0,0,0,0,0,0};
  for (int c = t; c < 3072; c += 256){
    float bb = BB0[c];
    #pragma unroll
    for (int oc = 0; oc < 8; oc++) part[oc] += bb*W0[oc*3072 + c];
  }
  __shared__ float red[4][8];
  int wv = t >> 6, lane = t & 63;
  #pragma unroll
  for (int oc = 0; oc < 8; oc++){
    float v = part[oc];
    for (int off = 32; off; off >>= 1) v += __shfl_down(v, off, 64);
    if (lane == 0) red[wv][oc] = v;
  }
  __syncthreads();
  if (t < 8) BCOL[48 + t] = red[0][t] + red[1][t] + red[2][t] + red[3][t];
}

// ---------- M_beta v3: MB[oc][dyx*128+ic] = sum_n wb0[n, j=(ic,dyx)] * w0[oc, n] ----------
// Parallel outer-product GEMM: grid (18 j-blocks, 24 n-blocks) = 432 blocks (v2 had 24
// blocks -> 0.9% occupancy, 276 us). Lane-contiguous j -> coalesced wb0 reads, each
// element read exactly once (7 MB); w0 reads wave-uniform (scalar).
__global__ __launch_bounds__(256) void k_mbeta(const void* __restrict__ wb0, const int* __restrict__ flag,
                                               const float* __restrict__ w0f, float* __restrict__ MB){
  int t = threadIdx.x;
  int jb = blockIdx.x, nb = blockIdx.y;
  int fl = *flag;
  int jl = t & 63, ng = t >> 6;
  int j = jb*64 + jl;
  int n0 = nb*128 + ng*32;
  float acc[8] = {0,0,0,0,0,0,0,0};
  for (int i = 0; i < 32; i++){
    int n = n0 + i;
    float wv = LD(wb0, (size_t)n*1152 + j, fl);
    #pragma unroll
    for (int oc = 0; oc < 8; oc++) acc[oc] += wv*w0f[oc*3072 + n];
  }
  int ic = j/9, dyx = j - ic*9;
  int jout = dyx*128 + ic;
  #pragma unroll
  for (int oc = 0; oc < 8; oc++) atomicAdd(&MB[oc*1152 + jout], acc[oc]);
}

__global__ __launch_bounds__(256) void k_wsm(const float* __restrict__ MB, bf16* __restrict__ WSMALL){
  int i = blockIdx.x*256 + threadIdx.x;
  if (i >= 9216) return;
  float v = MB[i];
  bf16 hi = f2b(v);
  WSMALL[48*1152 + i] = hi;
  WSMALL[56*1152 + i] = f2b(v - b2f(hi));
}

// ---------- merged small weight permutes: 4 tensors -> WSMALL slices, one launch ----------
__global__ __launch_bounds__(256) void k_permW4(const void* __restrict__ s11, const void* __restrict__ s13,
                                                const void* __restrict__ s17, const void* __restrict__ s19,
                                                bf16* __restrict__ WSMALL, const int* __restrict__ flag){
  int i = blockIdx.x*256 + threadIdx.x;
  if (i >= 55296) return;
  const void* src; bf16* dst; int idx;
  if      (i < 9216) { src = s11; dst = WSMALL;           idx = i; }
  else if (i < 18432){ src = s13; dst = WSMALL + 8*1152;  idx = i - 9216; }
  else if (i < 36864){ src = s17; dst = WSMALL + 16*1152; idx = i - 18432; }
  else               { src = s19; dst = WSMALL + 32*1152; idx = i - 36864; }
  int oc = idx / 1152, rr = idx % 1152;
  int dyx = rr >> 7, ic = rr & 127;
  dst[idx] = f2b(LD(src, (size_t)(oc*128 + ic)*9 + dyx, *flag));
}

// ---------- coalesced oc-major permute for WG0: (oc, ic128, 3,3) -> (oc, dyx, ic), bf16 ----------
__global__ __launch_bounds__(256) void k_permoc(const void* __restrict__ src, bf16* __restrict__ dst,
                                                const int* __restrict__ flag){
  __shared__ float lds[4608];
  int t = threadIdx.x;
  size_t base = (size_t)blockIdx.x*4608;
  int fl = *flag;
  for (int i = t; i < 4608; i += 256) lds[i] = LD(src, base + i, fl);
  __syncthreads();
  for (int i = t; i < 4608; i += 256){
    int ocl = i / 1152, r = i - ocl*1152;
    int dyx = r >> 7, ic = r & 127;
    dst[base + i] = f2b(lds[ocl*1152 + ic*9 + dyx]);
  }
}

// ---------- coalesced ws permute: (oc, ic768, 3,3) -> WSP[oc][dyx][ic] f32 ----------
__global__ __launch_bounds__(256) void k_permws(const void* __restrict__ ws0, const void* __restrict__ ws1,
                                                const void* __restrict__ ws2, const int* __restrict__ flag,
                                                float* __restrict__ WSP){
  __shared__ float lds[6912];
  int t = threadIdx.x;
  int oc = blockIdx.x;
  int l = oc >> 7, ocl = oc & 127;
  const void* src = l == 0 ? ws0 : (l == 1 ? ws1 : ws2);
  int fl = *flag;
  for (int i = t; i < 6912; i += 256) lds[i] = LD(src, (size_t)ocl*6912 + i, fl);
  __syncthreads();
  float* o = WSP + (size_t)oc*6912;
  for (int i = t; i < 6912; i += 256){
    int dyx = i / 768, ic = i - dyx*768;
    o[i] = lds[ic*9 + dyx];
  }
}

// ---------- segment means over 24x24 downsampled segmap ----------
__global__ __launch_bounds__(256) void k_seg_means(const void* __restrict__ f_sem, const int* __restrict__ flag,
                                                   const int* __restrict__ segmap,
                                                   float* __restrict__ means){
  int s = blockIdx.x, b = blockIdx.y, t = threadIdx.x;
  int fl = *flag;
  __shared__ int sid[576];
  for (int i = t; i < 576; i += 256){
    int y = i / 24, x = i % 24;
    int v = segmap[b*336*336 + (y*14)*336 + x*14];
    sid[i] = min(max(v, 0), 63);
  }
  __syncthreads();
  float a0=0.f, a1=0.f, a2=0.f; int cnt = 0;
  for (int i = 0; i < 576; i++){
    if (sid[i] == s){
      cnt++;
      a0 += LD(f_sem, (size_t)(b*768 + t      )*576 + i, fl);
      a1 += LD(f_sem, (size_t)(b*768 + t + 256)*576 + i, fl);
      a2 += LD(f_sem, (size_t)(b*768 + t + 512)*576 + i, fl);
    }
  }
  float inv = cnt > 0 ? 1.f/(float)cnt : 0.f;
  float* o = means + (size_t)(b*64 + s)*768;
  o[t] = a0*inv; o[t+256] = a1*inv; o[t+512] = a2*inv;
}

// ---------- TT[b][oc][dyx][s] = sum_ic WSP[oc][dyx][ic] * means[b][s][ic] ----------
__global__ __launch_bounds__(256) void k_tt(const float* __restrict__ WSP,
    const float* __restrict__ means, bf16* __restrict__ WTT){
  int bx = blockIdx.x;
  int dyx = bx / 24, ocb = bx % 24;
  int b = blockIdx.y, t = threadIdx.x;
  int ocg0 = ocb*16;
  __shared__ float wl[16][768];
  for (int ol = 0; ol < 16; ol++)
    for (int ic = t; ic < 768; ic += 256)
      wl[ol][ic] = WSP[(size_t)(ocg0 + ol)*6912 + (size_t)dyx*768 + ic];
  __syncthreads();
  int s = t & 63, og = t >> 6;
  const float* mr = means + ((size_t)b*64 + s)*768;
  float acc[4] = {0.f, 0.f, 0.f, 0.f};
  for (int ic = 0; ic < 768; ic += 4){
    float4 m = *reinterpret_cast<const float4*>(mr + ic);
    #pragma unroll
    for (int k = 0; k < 4; k++){
      const float* w = &wl[og + k*4][ic];
      acc[k] += m.x*w[0] + m.y*w[1] + m.z*w[2] + m.w*w[3];
    }
  }
  #pragma unroll
  for (int k = 0; k < 4; k++){
    bf16 h = f2b(acc[k]);
    size_t base = ((size_t)(b*384 + ocg0 + og + k*4))*1152 + (size_t)dyx*128 + s;
    WTT[base] = h;
    WTT[base + 64] = h;
  }
}

// ---------- per-pixel segment weights (antialiased bilinear 336->48), bf16 hi/lo out ----------
__global__ __launch_bounds__(192) void k_A(const int* __restrict__ segmap, bf16* __restrict__ AHL){
  int blk = blockIdx.x;
  int b = blk / PB, rem = blk % PB, yo = rem / 48, xo = rem % 48;
  __shared__ float accs[64];
  int t = threadIdx.x;
  if (t < 64) accs[t] = 0.f;
  __syncthreads();
  if (t < 169){
    int ty = t / 13, tx = t % 13;
    int jy = 7*yo - 3 + ty, jx = 7*xo - 3 + tx;
    if (jy >= 0 && jy < 336 && jx >= 0 && jx < 336){
      int wy = 7 - abs(ty - 6), wx = 7 - abs(tx - 6);
      int sv = segmap[b*336*336 + jy*336 + jx];
      sv = min(max(sv, 0), 63);
      atomicAdd(&accs[sv], (float)(wy*wx));
    }
  }
  int sumy = 0, sumx = 0;
  for (int k = 0; k < 13; k++){
    int jy = 7*yo - 3 + k; if (jy >= 0 && jy < 336) sumy += 7 - abs(k - 6);
    int jx = 7*xo - 3 + k; if (jx >= 0 && jx < 336) sumx += 7 - abs(k - 6);
  }
  __syncthreads();
  if (t < 64){
    float v = accs[t] / (float)(sumy*sumx);
    bf16 hi = f2b(v);
    AHL[(size_t)blk*128 + t] = hi;
    AHL[(size_t)blk*128 + 64 + t] = f2b(v - b2f(hi));
  }
}

// ---------- LN stats over x_main ----------
__global__ __launch_bounds__(256) void k_ln_partial(const void* __restrict__ x, const int* __restrict__ flag,
                                                    float2* __restrict__ part){
  int b = blockIdx.y, blk = blockIdx.x, t = threadIdx.x;
  int fl = *flag;
  size_t base = (size_t)b*7077888 + (size_t)blk*55296;
  float s = 0.f, sq = 0.f;
  for (int i = 0; i < 216; i++){
    float v = LD(x, base + t + i*256, fl);
    s += v; sq += v*v;
  }
  for (int off = 32; off; off >>= 1){ s += __shfl_down(s, off, 64); sq += __shfl_down(sq, off, 64); }
  __shared__ float ls[4], lq[4];
  int w = t >> 6, lane = t & 63;
  if (lane == 0){ ls[w] = s; lq[w] = sq; }
  __syncthreads();
  if (t == 0) part[b*128 + blk] = make_float2(ls[0]+ls[1]+ls[2]+ls[3], lq[0]+lq[1]+lq[2]+lq[3]);
}

__global__ void k_ln_final(const float2* __restrict__ part, float* __restrict__ stats){
  int b = blockIdx.x, t = threadIdx.x;
  float2 v = part[b*128 + t];
  float s = v.x, sq = v.y;
  for (int off = 32; off; off >>= 1){ s += __shfl_down(s, off, 64); sq += __shfl_down(sq, off, 64); }
  __shared__ float ls[2], lq[2];
  if ((t & 63) == 0){ ls[t>>6] = s; lq[t>>6] = sq; }
  __syncthreads();
  if (t == 0){
    s = ls[0]+ls[1]; sq = lq[0]+lq[1];
    const float N = 7077888.f;
    float mean = s/N; float var = sq/N - mean*mean; var = fmaxf(var, 0.f);
    stats[b*2] = mean; stats[b*2+1] = rsqrtf(var + 1e-12f);
  }
}

// ---------- softplus-in-place + LN stats (fused) ----------
__global__ __launch_bounds__(256) void k_spln(float* __restrict__ z, int cnt, float* __restrict__ stats){
  int b = blockIdx.x, t = threadIdx.x;
  float* p = z + (size_t)b*cnt;
  float s = 0.f, sq = 0.f;
  for (int i = t; i < cnt; i += 256){
    float v = softplus_f(p[i]);
    p[i] = v;
    s += v; sq += v*v;
  }
  for (int off = 32; off; off >>= 1){ s += __shfl_down(s, off, 64); sq += __shfl_down(sq, off, 64); }
  __shared__ float ls[4], lq[4];
  int w = t >> 6, lane = t & 63;
  if (lane == 0){ ls[w] = s; lq[w] = sq; }
  __syncthreads();
  if (t == 0){
    s = ls[0]+ls[1]+ls[2]+ls[3]; sq = lq[0]+lq[1]+lq[2]+lq[3];
    float mean = s/(float)cnt; float var = sq/(float)cnt - mean*mean; var = fmaxf(var, 0.f);
    stats[b*2] = mean; stats[b*2+1] = rsqrtf(var + 1e-12f);
  }
}

__global__ __launch_bounds__(256) void k_ln_small(const float* __restrict__ z, int cnt, float* __restrict__ stats){
  int b = blockIdx.x, t = threadIdx.x;
  const float* p = z + (size_t)b*cnt;
  float s = 0.f, sq = 0.f;
  for (int i = t; i < cnt; i += 256){ float v = p[i]; s += v; sq += v*v; }
  for (int off = 32; off; off >>= 1){ s += __shfl_down(s, off, 64); sq += __shfl_down(sq, off, 64); }
  __shared__ float ls[4], lq[4];
  int w = t >> 6, lane = t & 63;
  if (lane == 0){ ls[w] = s; lq[w] = sq; }
  __syncthreads();
  if (t == 0){
    s = ls[0]+ls[1]+ls[2]+ls[3]; sq = lq[0]+lq[1]+lq[2]+lq[3];
    float mean = s/(float)cnt; float var = sq/(float)cnt - mean*mean; var = fmaxf(var, 0.f);
    stats[b*2] = mean; stats[b*2+1] = rsqrtf(var + 1e-12f);
  }
}

// ---------- shared MFMA GEMM body (BK=64, 64x64 tile, 2-barrier structure) ----------
template<bool RELU, typename OT>
__device__ __forceinline__ void gemm_body(
    const bf16* __restrict__ Asrc, int AS, int acol, int ICW,
    const bf16* __restrict__ W, int K, size_t wbstride,
    const float* __restrict__ bp0, const float* __restrict__ bp1, const float* __restrict__ bp2, int seg,
    OT* __restrict__ out, int N, int ncb, int ldo, const bf16* __restrict__ zpad,
    int m0, int n0, bf16 (*Al)[64], bf16 (*Bl)[64])
{
  int t = threadIdx.x;
  int wv = t >> 6, lane = t & 63;
  int lr8 = lane >> 3, sseg = (lane & 7) ^ lr8;   // source 16B-seg (swizzled)
  int b = m0 >= PB ? 1 : 0;

  int ya[2], xa[2]; bool bv[2]; const bf16* wb[2];
  #pragma unroll
  for (int i = 0; i < 2; i++){
    int sp = (m0 - b*PB) + wv*16 + i*8 + lr8;
    ya[i] = sp / 48; xa[i] = sp % 48;
    int nrow = ncb + n0 + wv*16 + i*8 + lr8;
    bv[i] = nrow < N;
    wb[i] = W + (size_t)b*wbstride + (size_t)nrow*K + sseg*8;
  }

  int wm = (wv >> 1)*32, wn = (wv & 1)*32;
  int lrow = lane & 15, quad = lane >> 4;
  int sx = lrow & 7;
  int o0 = ((quad    ) ^ sx)*8;
  int o1 = ((quad + 4) ^ sx)*8;

  v4f acc00 = {0,0,0,0}, acc01 = {0,0,0,0}, acc10 = {0,0,0,0}, acc11 = {0,0,0,0};

  int dyx = 0, ic0 = 0;
  int ktn = K / 64;
  for (int kt = 0; kt < ktn; kt++){
    int dy = dyx/3 - 1, dx = dyx%3 - 1;
    #pragma unroll
    for (int i = 0; i < 2; i++){
      int ys = ya[i] + dy, xs = xa[i] + dx;
      const bf16* ga = (ys >= 0 && ys < 48 && xs >= 0 && xs < 48)
        ? Asrc + (size_t)(b*PB + ys*48 + xs)*AS + acol + ic0 + sseg*8 : zpad;
      gload_lds16(ga, &Al[wv*16 + i*8][0]);
      const bf16* gb = bv[i] ? wb[i] + kt*64 : zpad;
      gload_lds16(gb, &Bl[wv*16 + i*8][0]);
    }
    asm volatile("s_waitcnt vmcnt(0)" ::: "memory");
    __syncthreads();
    v8bf a00 = *reinterpret_cast<const v8bf*>(&Al[wm      + lrow][o0]);
    v8bf a10 = *reinterpret_cast<const v8bf*>(&Al[wm + 16 + lrow][o0]);
    v8bf a01 = *reinterpret_cast<const v8bf*>(&Al[wm      + lrow][o1]);
    v8bf a11 = *reinterpret_cast<const v8bf*>(&Al[wm + 16 + lrow][o1]);
    v8bf b00 = *reinterpret_cast<const v8bf*>(&Bl[wn      + lrow][o0]);
    v8bf b10 = *reinterpret_cast<const v8bf*>(&Bl[wn + 16 + lrow][o0]);
    v8bf b01 = *reinterpret_cast<const v8bf*>(&Bl[wn      + lrow][o1]);
    v8bf b11 = *reinterpret_cast<const v8bf*>(&Bl[wn + 16 + lrow][o1]);
    acc00 = __builtin_amdgcn_mfma_f32_16x16x32_bf16(a00, b00, acc00, 0, 0, 0);
    acc00 = __builtin_amdgcn_mfma_f32_16x16x32_bf16(a01, b01, acc00, 0, 0, 0);
    acc01 = __builtin_amdgcn_mfma_f32_16x16x32_bf16(a00, b10, acc01, 0, 0, 0);
    acc01 = __builtin_amdgcn_mfma_f32_16x16x32_bf16(a01, b11, acc01, 0, 0, 0);
    acc10 = __builtin_amdgcn_mfma_f32_16x16x32_bf16(a10, b00, acc10, 0, 0, 0);
    acc10 = __builtin_amdgcn_mfma_f32_16x16x32_bf16(a11, b01, acc10, 0, 0, 0);
    acc11 = __builtin_amdgcn_mfma_f32_16x16x32_bf16(a10, b10, acc11, 0, 0, 0);
    acc11 = __builtin_amdgcn_mfma_f32_16x16x32_bf16(a11, b11, acc11, 0, 0, 0);
    __syncthreads();
    ic0 += 64; if (ic0 == ICW){ ic0 = 0; dyx++; }
  }

  auto store_tile = [&](v4f a, int mi, int ni){
    int gcol = ncb + n0 + wn + ni*16 + lrow;
    if (gcol >= N) return;
    int sel = gcol / seg; sel = sel > 2 ? 2 : sel;
    const float* bp = sel == 0 ? bp0 : (sel == 1 ? bp1 : bp2);
    float bias = bp[gcol - sel*seg];
    int rowb = m0 + wm + mi*16 + quad*4;
    #pragma unroll
    for (int rg = 0; rg < 4; rg++){
      float v = a[rg] + bias;
      if (RELU) v = fmaxf(v, 0.f);
      if constexpr (sizeof(OT) == 2) out[(size_t)(rowb+rg)*ldo + (gcol - ncb)] = f2b(v);
      else                           out[(size_t)(rowb+rg)*ldo + (gcol - ncb)] = (OT)v;
    }
  };
  store_tile(acc00, 0, 0); store_tile(acc01, 0, 1);
  store_tile(acc10, 1, 0); store_tile(acc11, 1, 1);
}

template<bool RELU, typename OT>
__global__ __launch_bounds__(256) void k_gemm(
    const bf16* __restrict__ Asrc, int AS, int acol, int ICW,
    const bf16* __restrict__ W, int K, size_t wbstride,
    const float* __restrict__ bp0, const float* __restrict__ bp1, const float* __restrict__ bp2, int seg,
    OT* __restrict__ out, int N, int ncb, int ldo, const bf16* __restrict__ zpad)
{
  __shared__ __align__(16) bf16 Al[64][64];
  __shared__ __align__(16) bf16 Bl[64][64];
  gemm_body<RELU, OT>(Asrc, AS, acol, ICW, W, K, wbstride, bp0, bp1, bp2, seg,
                      out, N, ncb, ldo, zpad, blockIdx.x*64, blockIdx.y*64, Al, Bl);
}

// merged 3 small GEMMs: blockIdx.y selects {gamma1, beta1+gamma2, beta2+z0beta} config
__global__ __launch_bounds__(256) void k_gsmall(
    const bf16* __restrict__ HS, const bf16* __restrict__ WSMALL, const float* __restrict__ BCOL,
    float* __restrict__ GBS, const bf16* __restrict__ zpad)
{
  __shared__ __align__(16) bf16 Al[64][64];
  __shared__ __align__(16) bf16 Bl[64][64];
  int y = blockIdx.y;
  int acol = y == 0 ? 128 : (y == 1 ? 256 : 0);
  const bf16* W = WSMALL + (y == 0 ? 0 : (y == 1 ? 16*1152 : 48*1152));
  const float* bp = BCOL + (y == 0 ? 0 : (y == 1 ? 16 : 48));
  float* out = GBS + (y == 0 ? 0 : (y == 1 ? 16 : 48));
  int N = y == 1 ? 32 : 16;
  gemm_body<false, float>(HS, 384, acol, 128, W, 1152, 0, bp, bp, bp, 9999,
                          out, N, 0, 64, zpad, blockIdx.x*64, 0, Al, Bl);
}

// ---------- pure gamma GEMM: GAMMA[p][c] = im2col(HS)*WG0^T + bg0 ----------
__global__ __launch_bounds__(256, 4) void k_gg(
    const bf16* __restrict__ HS, const bf16* __restrict__ WG0, const float* __restrict__ BG0,
    bf16* __restrict__ GAMMA, const bf16* __restrict__ zpad)
{
  __shared__ __align__(16) bf16 Al[128][64];
  __shared__ __align__(16) bf16 Bl[128][64];
  int t = threadIdx.x;
  int m0 = blockIdx.x*128, n0 = blockIdx.y*128;
  int b = m0 >= PB ? 1 : 0;
  int wv = t >> 6, lane = t & 63;
  int lr8 = lane >> 3, sseg = (lane & 7) ^ lr8;
  int spbase = m0 - b*PB;

  int ya[4], xa[4];
  #pragma unroll
  for (int i = 0; i < 4; i++){
    int sp = spbase + wv*32 + i*8 + lr8;
    ya[i] = sp / 48; xa[i] = sp % 48;
  }
  const bf16* wgb = WG0 + (size_t)(n0 + wv*32 + lr8)*1152 + sseg*8;

  int wm = wv*32, lrow = lane & 15, quad = lane >> 4;
  int sx = lrow & 7;

  v4f acc[2][8];
  #pragma unroll
  for (int mi = 0; mi < 2; mi++)
    #pragma unroll
    for (int ni = 0; ni < 8; ni++) acc[mi][ni] = (v4f){0,0,0,0};

  for (int kt = 0; kt < 18; kt++){
    int dyx = kt >> 1, icr = (kt & 1) << 6;
    int dy = dyx/3 - 1, dx = dyx%3 - 1;
    #pragma unroll
    for (int i = 0; i < 4; i++){
      int ys = ya[i] + dy, xs = xa[i] + dx;
      const bf16* ga = (ys >= 0 && ys < 48 && xs >= 0 && xs < 48)
        ? HS + (size_t)(b*PB + ys*48 + xs)*384 + icr + sseg*8 : zpad;
      gload_lds16(ga, &Al[wv*32 + i*8][0]);
      gload_lds16(wgb + (size_t)(i*8)*1152 + dyx*128 + icr, &Bl[wv*32 + i*8][0]);
    }
    asm volatile("s_waitcnt vmcnt(0)" ::: "memory");
    __syncthreads();
    #pragma unroll
    for (int kh = 0; kh < 2; kh++){
      int oa = ((kh*4 + quad) ^ sx)*8;
      v8bf a0 = *reinterpret_cast<const v8bf*>(&Al[wm      + lrow][oa]);
      v8bf a1 = *reinterpret_cast<const v8bf*>(&Al[wm + 16 + lrow][oa]);
      #pragma unroll
      for (int ni = 0; ni < 8; ni++){
        v8bf bn = *reinterpret_cast<const v8bf*>(&Bl[ni*16 + lrow][oa]);
        acc[0][ni] = __builtin_amdgcn_mfma_f32_16x16x32_bf16(a0, bn, acc[0][ni], 0, 0, 0);
        acc[1][ni] = __builtin_amdgcn_mfma_f32_16x16x32_bf16(a1, bn, acc[1][ni], 0, 0, 0);
      }
    }
    __syncthreads();
  }

  #pragma unroll
  for (int mi = 0; mi < 2; mi++){
    int pr = m0 + wm + mi*16 + quad*4;
    #pragma unroll
    for (int ni = 0; ni < 8; ni++){
      int gc = n0 + ni*16 + lrow;
      float bg = BG0[gc];
      #pragma unroll
      for (int rg = 0; rg < 4; rg++)
        GAMMA[(size_t)(pr + rg)*3072 + gc] = f2b(acc[mi][ni][rg] + bg);
    }
  }
}

// ---------- z0 contraction v2: z0[p,oc] += sum_c xn[p,c]*(1+gamma[p,c])*w0[oc,c] ----------
__global__ __launch_bounds__(256) void k_zc(
    const void* __restrict__ x, const bf16* __restrict__ GAMMA, const int* __restrict__ flag,
    const float* __restrict__ stats, const float* __restrict__ w0f, float* __restrict__ z0)
{
  __shared__ bf16 gmT[64][130];     // [c][px] 64c x 128px; word-stride 65 (odd) -> conflict-free
  __shared__ float w0l[8][128];
  __shared__ float red[4][128][9];  // pad 9 -> 4-way max on writes
  int t = threadIdx.x;
  int p0 = blockIdx.x*128, cb = blockIdx.y;
  int b = p0 / PB;
  int spbase = p0 - b*PB;
  int fl = *flag;
  float mean = stats[b*2], rstd = stats[b*2+1];
  int lane = t & 63, cg = t >> 6;
  int c0b = cb*128;

  for (int i = t; i < 1024; i += 256) w0l[i >> 7][i & 127] = w0f[(size_t)(i >> 7)*3072 + c0b + (i & 127)];

  float acc0[8], acc1[8];
  #pragma unroll
  for (int oc = 0; oc < 8; oc++){ acc0[oc] = 0.f; acc1[oc] = 0.f; }

  for (int ct = 0; ct < 2; ct++){
    int c0 = c0b + ct*64;
    {
      int cl = t & 63, pr = t >> 6;
      #pragma unroll
      for (int k = 0; k < 32; k++){
        int p = pr + k*4;
        gmT[cl][p] = GAMMA[(size_t)(p0 + p)*3072 + c0 + cl];
      }
    }
    __syncthreads();
    #pragma unroll
    for (int ci = 0; ci < 16; ci++){
      int c = cg*16 + ci;
      float xv0, xv1;
      if (fl){
        const float* xp = (const float*)x + ((size_t)(b*3072 + c0 + c))*2304 + spbase + lane*2;
        float2 v = *reinterpret_cast<const float2*>(xp);
        xv0 = v.x; xv1 = v.y;
      } else {
        const bf16* xp = (const bf16*)x + ((size_t)(b*3072 + c0 + c))*2304 + spbase + lane*2;
        xv0 = b2f(xp[0]); xv1 = b2f(xp[1]);
      }
      float t0 = (xv0 - mean)*rstd*(1.f + b2f(gmT[c][lane*2]));
      float t1 = (xv1 - mean)*rstd*(1.f + b2f(gmT[c][lane*2 + 1]));
      #pragma unroll
      for (int oc = 0; oc < 8; oc++){
        float wv = w0l[oc][ct*64 + c];
        acc0[oc] += t0*wv; acc1[oc] += t1*wv;
      }
    }
    __syncthreads();
  }
  #pragma unroll
  for (int oc = 0; oc < 8; oc++){
    red[cg][lane*2    ][oc] = acc0[oc];
    red[cg][lane*2 + 1][oc] = acc1[oc];
  }
  __syncthreads();
  #pragma unroll
  for (int j = 0; j < 4; j++){
    int idx = t + j*256;          // 1024 = 128 px * 8 oc
    int p2 = idx >> 3, o2 = idx & 7;
    float s = red[0][p2][o2] + red[1][p2][o2] + red[2][p2][o2] + red[3][p2][o2];
    atomicAdd(&z0[(size_t)(p0 + p2)*8 + o2], s);
  }
}

// ---------- z0 init: bias0 + beta-contraction (GBS cols 48..55 hi + 56..63 lo) ----------
__global__ __launch_bounds__(256) void k_z0init(const float* __restrict__ b0f, const float* __restrict__ GBS,
                                                float* __restrict__ z0){
  int i = blockIdx.x*256 + threadIdx.x;
  if (i >= 36864) return;
  int p = i >> 3, oc = i & 7;
  z0[i] = b0f[oc] + GBS[(size_t)p*64 + 48 + oc] + GBS[(size_t)p*64 + 56 + oc];
}

__global__ __launch_bounds__(256) void k_F1(const float* __restrict__ z0, const float* __restrict__ GBS,
    const float* __restrict__ stats, const float* __restrict__ w1f, const float* __restrict__ b1f,
    float* __restrict__ z1){
  int p = blockIdx.x*256 + threadIdx.x;
  if (p >= PTOT) return;
  int b = p / PB;
  float mean = stats[b*2], rstd = stats[b*2+1];
  const float* zr = z0 + (size_t)p*8;
  const float* gr = GBS + (size_t)p*64;
  float yv[8];
  #pragma unroll
  for (int c = 0; c < 8; c++) yv[c] = (zr[c] - mean)*rstd*(1.f + gr[c]) + gr[8 + c];
  #pragma unroll
  for (int oc = 0; oc < 16; oc++){
    float s = b1f[oc];
    #pragma unroll
    for (int c = 0; c < 8; c++) s += yv[c]*w1f[oc*8 + c];
    z1[(size_t)p*16 + oc] = softplus_f(s);
  }
}

__global__ __launch_bounds__(256) void k_F2(const float* __restrict__ z1, const float* __restrict__ GBS,
    const float* __restrict__ stats, const float* __restrict__ w2f, const float* __restrict__ b2f,
    void* __restrict__ outp, const int* __restrict__ flag){
  int p = blockIdx.x*256 + threadIdx.x;
  if (p >= PTOT) return;
  int b = p / PB;
  float mean = stats[b*2], rstd = stats[b*2+1];
  const float* zr = z1 + (size_t)p*16;
  const float* gr = GBS + (size_t)p*64 + 16;
  float s = b2f[0];
  #pragma unroll
  for (int c = 0; c < 16; c++){
    float yv = (zr[c] - mean)*rstd*(1.f + gr[c]) + gr[16 + c];
    s += yv*w2f[c];
  }
  float r = softplus_f(s);
  if (*flag) ((float*)outp)[p] = r;
  else       ((bf16*)outp)[p] = f2b(r);
}

extern "C" void kernel_launch(void* const* d_in, const int* in_sizes, int n_in,
                              void* d_out, int out_size, void* d_ws, size_t ws_size,
                              hipStream_t stream){
  const void* x_main = d_in[0];
  const void* f_sem  = d_in[1];
  const int*  segmap = (const int*)d_in[2];

  char* ws = (char*)d_ws;
  size_t o = 0;
  auto alloc = [&](size_t bytes){ size_t r = o; o = (o + bytes + 255) & ~(size_t)255; return r; };
  float* MEANS = (float*)(ws + alloc(98304u*4));
  bf16*  AHL   = (bf16*) (ws + alloc(589824u*2));    // PTOT*128 hi/lo A weights
  bf16*  WTT   = (bf16*) (ws + alloc(884736u*2));    // 2*384*1152 folded conv weights
  bf16*  WG0   = (bf16*) (ws + alloc(3538944u*2));
  bf16*  WSMALL= (bf16*) (ws + alloc(73728u*2));
  bf16*  HS    = (bf16*) (ws + alloc(1769472u*2));
  float* WSP   = (float*)(ws + alloc(2654208u*4));   // 384*6912 permuted ws (f32)
  bf16*  GAMMA = (bf16*) (ws + alloc(14155776u*2));  // 4608*3072 gamma (layer 0)
  float* GBS   = (float*)(ws + alloc(294912u*4));
  float* Z0    = (float*)(ws + alloc(36864u*4));
  float* Z1    = (float*)(ws + alloc(73728u*4));
  float2* LNP  = (float2*)(ws + alloc(256u*8));
  float* STATS = (float*)(ws + alloc(16u*4));
  int*   FLAG  = (int*)  (ws + alloc(64u));
  float* SMALLF= (float*)(ws + alloc(31321u*4));
  float* MB    = (float*)(ws + alloc(9216u*4));
  float* BCOL  = (float*)(ws + alloc(64u*4));
  bf16*  ZPAD  = (bf16*) (ws + alloc(512u));

  float *BS0=SMALLF+0, *BS1=SMALLF+128, *BS2=SMALLF+256;
  float *BG0=SMALLF+384;
  float *W0=SMALLF+6576, *B0=SMALLF+31152;
  float *W1=SMALLF+31160, *B1=SMALLF+31288;
  float *W2=SMALLF+31304, *B2=SMALLF+31320;

  k_sniff<<<1, 256, 0, stream>>>((const unsigned*)x_main, FLAG, (float*)ZPAD);
  k_cvt_small<<<159, 256, 0, stream>>>(d_in[4], d_in[10], d_in[16], d_in[6], d_in[8],
      d_in[12], d_in[14], d_in[18], d_in[20], d_in[21], d_in[22], d_in[23], d_in[24],
      d_in[25], d_in[26], SMALLF, FLAG, MB);
  k_bcol<<<1, 256, 0, stream>>>(SMALLF, BCOL);
  k_mbeta<<<dim3(18,24), 256, 0, stream>>>(d_in[7], FLAG, W0, MB);
  k_wsm<<<36, 256, 0, stream>>>(MB, WSMALL);

  k_permoc<<<768, 256, 0, stream>>>(d_in[5], WG0, FLAG);          // coalesced WG0 permute
  k_permws<<<384, 256, 0, stream>>>(d_in[3], d_in[9], d_in[15], FLAG, WSP);
  k_permW4<<<216, 256, 0, stream>>>(d_in[11], d_in[13], d_in[17], d_in[19], WSMALL, FLAG);

  k_ln_partial<<<dim3(128,2), 256, 0, stream>>>(x_main, FLAG, LNP);
  k_ln_final<<<2, 128, 0, stream>>>(LNP, STATS);
  k_seg_means<<<dim3(64,2), 256, 0, stream>>>(f_sem, FLAG, segmap, MEANS);
  k_tt<<<dim3(216,2), 256, 0, stream>>>(WSP, MEANS, WTT);
  k_A<<<PTOT, 192, 0, stream>>>(segmap, AHL);

  // G1: h = relu(conv3x3(sem, ws_l)) for all 3 layers -> HS (4608,384), folded-weight K=1152
  k_gemm<true, bf16><<<dim3(72,6), 256, 0, stream>>>(AHL, 128, 0, 128, WTT, 1152, (size_t)384*1152,
      BS0, BS1, BS2, 128, HS, 384, 0, 384, ZPAD);
  // merged small GEMMs (gamma1/beta1/gamma2/beta2/z0beta)
  k_gsmall<<<dim3(72,3), 256, 0, stream>>>(HS, WSMALL, BCOL, GBS, ZPAD);

  // layer-0 split: gamma GEMM -> GAMMA, then streaming z0 contraction
  k_z0init<<<144, 256, 0, stream>>>(B0, GBS, Z0);
  k_gg<<<dim3(36,24), 256, 0, stream>>>(HS, WG0, BG0, GAMMA, ZPAD);
  k_zc<<<dim3(36,24), 256, 0, stream>>>(x_main, GAMMA, FLAG, STATS, W0, Z0);
  k_spln<<<2, 256, 0, stream>>>(Z0, 18432, STATS + 4);

  k_F1<<<18, 256, 0, stream>>>(Z0, GBS, STATS + 4, W1, B1, Z1);
  k_ln_small<<<2, 256, 0, stream>>>(Z1, 36864, STATS + 8);
  k_F2<<<18, 256, 0, stream>>>(Z1, GBS, STATS + 8, W2, B2, d_out, FLAG);
}

// Round 9
// 529.477 us; speedup vs baseline: 1.4723x; 1.0313x over previous
//
#include <hip/hip_runtime.h>
#include <hip/hip_bf16.h>

typedef __hip_bfloat16 bf16;
typedef __bf16 v8bf __attribute__((ext_vector_type(8)));
typedef float v4f __attribute__((ext_vector_type(4)));

#define PB 2304
#define PTOT 4608

__device__ __forceinline__ float b2f(bf16 x){ return __bfloat162float(x); }
__device__ __forceinline__ bf16 f2b(float x){ return __float2bfloat16(x); }
__device__ __forceinline__ float softplus_f(float x){
  return fmaxf(x, 0.f) + log1pf(expf(-fabsf(x)));
}
__device__ __forceinline__ float LD(const void* src, size_t i, int fl){
  return fl ? ((const float*)src)[i] : b2f(((const bf16*)src)[i]);
}

// async global->LDS DMA, 16B per lane; LDS dest is wave-uniform base + lane*16
__device__ __forceinline__ void gload_lds16(const void* g, void* l){
  __builtin_amdgcn_global_load_lds(
      (const __attribute__((address_space(1))) void*)g,
      (__attribute__((address_space(3))) void*)l, 16, 0, 0);
}

// ---------- dtype sniffer (flag=1 if f32) + ZPAD zeroing ----------
__global__ __launch_bounds__(256) void k_sniff(const unsigned* __restrict__ x, int* __restrict__ flag,
                                               float* __restrict__ zp){
  int t = threadIdx.x;
  if (t < 128) zp[t] = 0.f;
  int cnt = 0;
  for (int i = t; i < 4096; i += 256){
    unsigned e = (x[i] >> 8) & 0x7F;
    if (e >= 0x38 && e <= 0x42) cnt++;
  }
  for (int off = 32; off; off >>= 1) cnt += __shfl_down(cnt, off, 64);
  __shared__ int sc[4];
  if ((t & 63) == 0) sc[t >> 6] = cnt;
  __syncthreads();
  if (t == 0) *flag = (sc[0]+sc[1]+sc[2]+sc[3] < 2048) ? 1 : 0;
}

// ---------- merged small-tensor canonicalization to f32 + MB/TTACC zeroing ----------
__global__ __launch_bounds__(256) void k_cvt_small(
    const void* s4, const void* s10, const void* s16, const void* s6, const void* s8,
    const void* s12, const void* s14, const void* s18, const void* s20,
    const void* s21, const void* s22, const void* s23, const void* s24,
    const void* s25, const void* s26,
    float* __restrict__ dst, const int* __restrict__ flag, float* __restrict__ MB,
    float* __restrict__ TTACC){
  int i = blockIdx.x*256 + threadIdx.x;
  if (i >= 482905) return;
  if (i >= 40537){ TTACC[i - 40537] = 0.f; return; }
  if (i >= 31321){ MB[i - 31321] = 0.f; return; }
  int fl = *flag;
  const void* src; size_t off;
  if      (i < 128)   { src = s4;  off = i; }
  else if (i < 256)   { src = s10; off = i - 128; }
  else if (i < 384)   { src = s16; off = i - 256; }
  else if (i < 3456)  { src = s6;  off = i - 384; }
  else if (i < 6528)  { src = s8;  off = i - 3456; }
  else if (i < 6536)  { src = s12; off = i - 6528; }
  else if (i < 6544)  { src = s14; off = i - 6536; }
  else if (i < 6560)  { src = s18; off = i - 6544; }
  else if (i < 6576)  { src = s20; off = i - 6560; }
  else if (i < 31152) { src = s21; off = i - 6576; }
  else if (i < 31160) { src = s22; off = i - 31152; }
  else if (i < 31288) { src = s23; off = i - 31160; }
  else if (i < 31304) { src = s24; off = i - 31288; }
  else if (i < 31320) { src = s25; off = i - 31304; }
  else                { src = s26; off = i - 31320; }
  dst[i] = LD(src, off, fl);
}

// ---------- BCOL[64]: per-column biases for the small GEMMs ----------
__global__ __launch_bounds__(256) void k_bcol(const float* __restrict__ SMALLF, float* __restrict__ BCOL){
  int t = threadIdx.x;
  const float* BG1 = SMALLF + 6528; const float* BB1 = SMALLF + 6536;
  const float* BG2 = SMALLF + 6544; const float* BB2 = SMALLF + 6560;
  const float* BB0 = SMALLF + 3456; const float* W0  = SMALLF + 6576;
  if (t < 8)       BCOL[t] = BG1[t];
  else if (t < 16) BCOL[t] = BB1[t-8];
  else if (t < 32) BCOL[t] = BG2[t-16];
  else if (t < 48) BCOL[t] = BB2[t-32];
  else if (t < 64) BCOL[t] = 0.f;
  float part[8] = {0,0,0,0,0,0,0,0};
  for (int c = t; c < 3072; c += 256){
    float bb = BB0[c];
    #pragma unroll
    for (int oc = 0; oc < 8; oc++) part[oc] += bb*W0[oc*3072 + c];
  }
  __shared__ float red[4][8];
  int wv = t >> 6, lane = t & 63;
  #pragma unroll
  for (int oc = 0; oc < 8; oc++){
    float v = part[oc];
    for (int off = 32; off; off >>= 1) v += __shfl_down(v, off, 64);
    if (lane == 0) red[wv][oc] = v;
  }
  __syncthreads();
  if (t < 8) BCOL[48 + t] = red[0][t] + red[1][t] + red[2][t] + red[3][t];
}

// ---------- M_beta v3: MB[oc][dyx*128+ic] = sum_n wb0[n, j=(ic,dyx)] * w0[oc, n] ----------
__global__ __launch_bounds__(256) void k_mbeta(const void* __restrict__ wb0, const int* __restrict__ flag,
                                               const float* __restrict__ w0f, float* __restrict__ MB){
  int t = threadIdx.x;
  int jb = blockIdx.x, nb = blockIdx.y;
  int fl = *flag;
  int jl = t & 63, ng = t >> 6;
  int j = jb*64 + jl;
  int n0 = nb*128 + ng*32;
  float acc[8] = {0,0,0,0,0,0,0,0};
  for (int i = 0; i < 32; i++){
    int n = n0 + i;
    float wv = LD(wb0, (size_t)n*1152 + j, fl);
    #pragma unroll
    for (int oc = 0; oc < 8; oc++) acc[oc] += wv*w0f[oc*3072 + n];
  }
  int ic = j/9, dyx = j - ic*9;
  int jout = dyx*128 + ic;
  #pragma unroll
  for (int oc = 0; oc < 8; oc++) atomicAdd(&MB[oc*1152 + jout], acc[oc]);
}

__global__ __launch_bounds__(256) void k_wsm(const float* __restrict__ MB, bf16* __restrict__ WSMALL){
  int i = blockIdx.x*256 + threadIdx.x;
  if (i >= 9216) return;
  float v = MB[i];
  bf16 hi = f2b(v);
  WSMALL[48*1152 + i] = hi;
  WSMALL[56*1152 + i] = f2b(v - b2f(hi));
}

// ---------- merged small weight permutes: 4 tensors -> WSMALL slices, one launch ----------
__global__ __launch_bounds__(256) void k_permW4(const void* __restrict__ s11, const void* __restrict__ s13,
                                                const void* __restrict__ s17, const void* __restrict__ s19,
                                                bf16* __restrict__ WSMALL, const int* __restrict__ flag){
  int i = blockIdx.x*256 + threadIdx.x;
  if (i >= 55296) return;
  const void* src; bf16* dst; int idx;
  if      (i < 9216) { src = s11; dst = WSMALL;           idx = i; }
  else if (i < 18432){ src = s13; dst = WSMALL + 8*1152;  idx = i - 9216; }
  else if (i < 36864){ src = s17; dst = WSMALL + 16*1152; idx = i - 18432; }
  else               { src = s19; dst = WSMALL + 32*1152; idx = i - 36864; }
  int oc = idx / 1152, rr = idx % 1152;
  int dyx = rr >> 7, ic = rr & 127;
  dst[idx] = f2b(LD(src, (size_t)(oc*128 + ic)*9 + dyx, *flag));
}

// ---------- coalesced oc-major permute for WG0: (oc, ic128, 3,3) -> (oc, dyx, ic), bf16 ----------
__global__ __launch_bounds__(256) void k_permoc(const void* __restrict__ src, bf16* __restrict__ dst,
                                                const int* __restrict__ flag){
  __shared__ float lds[4608];
  int t = threadIdx.x;
  size_t base = (size_t)blockIdx.x*4608;
  int fl = *flag;
  for (int i = t; i < 4608; i += 256) lds[i] = LD(src, base + i, fl);
  __syncthreads();
  for (int i = t; i < 4608; i += 256){
    int ocl = i / 1152, r = i - ocl*1152;
    int dyx = r >> 7, ic = r & 127;
    dst[base + i] = f2b(lds[ocl*1152 + ic*9 + dyx]);
  }
}

// ---------- coalesced ws permute: (oc, ic768, 3,3) -> WSP[oc][dyx][ic] f32 ----------
__global__ __launch_bounds__(256) void k_permws(const void* __restrict__ ws0, const void* __restrict__ ws1,
                                                const void* __restrict__ ws2, const int* __restrict__ flag,
                                                float* __restrict__ WSP){
  __shared__ float lds[6912];
  int t = threadIdx.x;
  int oc = blockIdx.x;
  int l = oc >> 7, ocl = oc & 127;
  const void* src = l == 0 ? ws0 : (l == 1 ? ws1 : ws2);
  int fl = *flag;
  for (int i = t; i < 6912; i += 256) lds[i] = LD(src, (size_t)ocl*6912 + i, fl);
  __syncthreads();
  float* o = WSP + (size_t)oc*6912;
  for (int i = t; i < 6912; i += 256){
    int dyx = i / 768, ic = i - dyx*768;
    o[i] = lds[ic*9 + dyx];
  }
}

// ---------- segment means over 24x24 downsampled segmap ----------
__global__ __launch_bounds__(256) void k_seg_means(const void* __restrict__ f_sem, const int* __restrict__ flag,
                                                   const int* __restrict__ segmap,
                                                   float* __restrict__ means){
  int s = blockIdx.x, b = blockIdx.y, t = threadIdx.x;
  int fl = *flag;
  __shared__ int sid[576];
  for (int i = t; i < 576; i += 256){
    int y = i / 24, x = i % 24;
    int v = segmap[b*336*336 + (y*14)*336 + x*14];
    sid[i] = min(max(v, 0), 63);
  }
  __syncthreads();
  float a0=0.f, a1=0.f, a2=0.f; int cnt = 0;
  for (int i = 0; i < 576; i++){
    if (sid[i] == s){
      cnt++;
      a0 += LD(f_sem, (size_t)(b*768 + t      )*576 + i, fl);
      a1 += LD(f_sem, (size_t)(b*768 + t + 256)*576 + i, fl);
      a2 += LD(f_sem, (size_t)(b*768 + t + 512)*576 + i, fl);
    }
  }
  float inv = cnt > 0 ? 1.f/(float)cnt : 0.f;
  float* o = means + (size_t)(b*64 + s)*768;
  o[t] = a0*inv; o[t+256] = a1*inv; o[t+512] = a2*inv;
}

// ---------- k_tt v3: TTACC[b][oc][dyx][s] += sum_{ic in third} WSP[oc][dyx][ic]*means[b][s][ic] ----------
// v2 was 60us @ Occ 16% (432 blocks, 49KB LDS, 192-iter serial L2 loads). v3: grid
// (216,2,3)=1296 blocks (ic 3-way split), 16KB LDS, 64-iter inner. f32 atomics into TTACC.
__global__ __launch_bounds__(256) void k_tt(const float* __restrict__ WSP,
    const float* __restrict__ means, float* __restrict__ TTACC){
  __shared__ float wl[16][256];
  int bx = blockIdx.x;
  int dyx = bx / 24, ocb = bx % 24;
  int b = blockIdx.y, icb = blockIdx.z, t = threadIdx.x;
  int ocg0 = ocb*16;
  int ic0 = icb*256;
  for (int i = t; i < 4096; i += 256){
    int oc = i >> 8, ic = i & 255;
    wl[oc][ic] = WSP[(size_t)(ocg0 + oc)*6912 + (size_t)dyx*768 + ic0 + ic];
  }
  __syncthreads();
  int s = t & 63, og = t >> 6;
  const float* mr = means + ((size_t)b*64 + s)*768 + ic0;
  float acc[4] = {0.f, 0.f, 0.f, 0.f};
  for (int ic = 0; ic < 256; ic += 4){
    float4 m = *reinterpret_cast<const float4*>(mr + ic);
    #pragma unroll
    for (int k = 0; k < 4; k++){
      const float* w = &wl[og*4 + k][ic];
      acc[k] += m.x*w[0] + m.y*w[1] + m.z*w[2] + m.w*w[3];
    }
  }
  size_t base = ((size_t)(b*384 + ocg0 + og*4)*9 + dyx)*64 + s;
  #pragma unroll
  for (int k = 0; k < 4; k++)
    atomicAdd(&TTACC[base + (size_t)k*576], acc[k]);
}

// ---------- TTACC -> WTT (bf16, hi/lo duplicated) ----------
__global__ __launch_bounds__(256) void k_wtt(const float* __restrict__ TTACC, bf16* __restrict__ WTT){
  int i = blockIdx.x*256 + threadIdx.x;
  if (i >= 442368) return;
  int s = i & 63;
  int r = i >> 6;
  int dyx = r % 9, q = r / 9;    // q = b*384 + oc
  bf16 h = f2b(TTACC[i]);
  size_t base = (size_t)q*1152 + dyx*128 + s;
  WTT[base] = h;
  WTT[base + 64] = h;
}

// ---------- per-pixel segment weights (antialiased bilinear 336->48), bf16 hi/lo out ----------
__global__ __launch_bounds__(192) void k_A(const int* __restrict__ segmap, bf16* __restrict__ AHL){
  int blk = blockIdx.x;
  int b = blk / PB, rem = blk % PB, yo = rem / 48, xo = rem % 48;
  __shared__ float accs[64];
  int t = threadIdx.x;
  if (t < 64) accs[t] = 0.f;
  __syncthreads();
  if (t < 169){
    int ty = t / 13, tx = t % 13;
    int jy = 7*yo - 3 + ty, jx = 7*xo - 3 + tx;
    if (jy >= 0 && jy < 336 && jx >= 0 && jx < 336){
      int wy = 7 - abs(ty - 6), wx = 7 - abs(tx - 6);
      int sv = segmap[b*336*336 + jy*336 + jx];
      sv = min(max(sv, 0), 63);
      atomicAdd(&accs[sv], (float)(wy*wx));
    }
  }
  int sumy = 0, sumx = 0;
  for (int k = 0; k < 13; k++){
    int jy = 7*yo - 3 + k; if (jy >= 0 && jy < 336) sumy += 7 - abs(k - 6);
    int jx = 7*xo - 3 + k; if (jx >= 0 && jx < 336) sumx += 7 - abs(k - 6);
  }
  __syncthreads();
  if (t < 64){
    float v = accs[t] / (float)(sumy*sumx);
    bf16 hi = f2b(v);
    AHL[(size_t)blk*128 + t] = hi;
    AHL[(size_t)blk*128 + 64 + t] = f2b(v - b2f(hi));
  }
}

// ---------- LN stats over x_main (vectorized loads: 8 bf16 / 4 f32 per access) ----------
__global__ __launch_bounds__(256) void k_ln_partial(const void* __restrict__ x, const int* __restrict__ flag,
                                                    float2* __restrict__ part){
  int b = blockIdx.y, blk = blockIdx.x, t = threadIdx.x;
  int fl = *flag;
  size_t base = (size_t)b*7077888 + (size_t)blk*55296;
  float s = 0.f, sq = 0.f;
  if (fl){
    const float* xp = (const float*)x + base + t*4;
    for (int i = 0; i < 54; i++){
      float4 v = *reinterpret_cast<const float4*>(xp + i*1024);
      s += v.x + v.y + v.z + v.w;
      sq += v.x*v.x + v.y*v.y + v.z*v.z + v.w*v.w;
    }
  } else {
    const bf16* xp = (const bf16*)x + base + t*8;
    for (int i = 0; i < 27; i++){
      v8bf v = *reinterpret_cast<const v8bf*>(xp + i*2048);
      #pragma unroll
      for (int j = 0; j < 8; j++){ float f = (float)v[j]; s += f; sq += f*f; }
    }
  }
  for (int off = 32; off; off >>= 1){ s += __shfl_down(s, off, 64); sq += __shfl_down(sq, off, 64); }
  __shared__ float ls[4], lq[4];
  int w = t >> 6, lane = t & 63;
  if (lane == 0){ ls[w] = s; lq[w] = sq; }
  __syncthreads();
  if (t == 0) part[b*128 + blk] = make_float2(ls[0]+ls[1]+ls[2]+ls[3], lq[0]+lq[1]+lq[2]+lq[3]);
}

__global__ void k_ln_final(const float2* __restrict__ part, float* __restrict__ stats){
  int b = blockIdx.x, t = threadIdx.x;
  float2 v = part[b*128 + t];
  float s = v.x, sq = v.y;
  for (int off = 32; off; off >>= 1){ s += __shfl_down(s, off, 64); sq += __shfl_down(sq, off, 64); }
  __shared__ float ls[2], lq[2];
  if ((t & 63) == 0){ ls[t>>6] = s; lq[t>>6] = sq; }
  __syncthreads();
  if (t == 0){
    s = ls[0]+ls[1]; sq = lq[0]+lq[1];
    const float N = 7077888.f;
    float mean = s/N; float var = sq/N - mean*mean; var = fmaxf(var, 0.f);
    stats[b*2] = mean; stats[b*2+1] = rsqrtf(var + 1e-12f);
  }
}

// ---------- softplus-in-place + LN stats (fused) ----------
__global__ __launch_bounds__(256) void k_spln(float* __restrict__ z, int cnt, float* __restrict__ stats){
  int b = blockIdx.x, t = threadIdx.x;
  float* p = z + (size_t)b*cnt;
  float s = 0.f, sq = 0.f;
  for (int i = t; i < cnt; i += 256){
    float v = softplus_f(p[i]);
    p[i] = v;
    s += v; sq += v*v;
  }
  for (int off = 32; off; off >>= 1){ s += __shfl_down(s, off, 64); sq += __shfl_down(sq, off, 64); }
  __shared__ float ls[4], lq[4];
  int w = t >> 6, lane = t & 63;
  if (lane == 0){ ls[w] = s; lq[w] = sq; }
  __syncthreads();
  if (t == 0){
    s = ls[0]+ls[1]+ls[2]+ls[3]; sq = lq[0]+lq[1]+lq[2]+lq[3];
    float mean = s/(float)cnt; float var = sq/(float)cnt - mean*mean; var = fmaxf(var, 0.f);
    stats[b*2] = mean; stats[b*2+1] = rsqrtf(var + 1e-12f);
  }
}

__global__ __launch_bounds__(256) void k_ln_small(const float* __restrict__ z, int cnt, float* __restrict__ stats){
  int b = blockIdx.x, t = threadIdx.x;
  const float* p = z + (size_t)b*cnt;
  float s = 0.f, sq = 0.f;
  for (int i = t; i < cnt; i += 256){ float v = p[i]; s += v; sq += v*v; }
  for (int off = 32; off; off >>= 1){ s += __shfl_down(s, off, 64); sq += __shfl_down(sq, off, 64); }
  __shared__ float ls[4], lq[4];
  int w = t >> 6, lane = t & 63;
  if (lane == 0){ ls[w] = s; lq[w] = sq; }
  __syncthreads();
  if (t == 0){
    s = ls[0]+ls[1]+ls[2]+ls[3]; sq = lq[0]+lq[1]+lq[2]+lq[3];
    float mean = s/(float)cnt; float var = sq/(float)cnt - mean*mean; var = fmaxf(var, 0.f);
    stats[b*2] = mean; stats[b*2+1] = rsqrtf(var + 1e-12f);
  }
}

// ---------- shared MFMA GEMM body (BK=64, 64x64 tile, 2-barrier structure) ----------
template<bool RELU, typename OT>
__device__ __forceinline__ void gemm_body(
    const bf16* __restrict__ Asrc, int AS, int acol, int ICW,
    const bf16* __restrict__ W, int K, size_t wbstride,
    const float* __restrict__ bp0, const float* __restrict__ bp1, const float* __restrict__ bp2, int seg,
    OT* __restrict__ out, int N, int ncb, int ldo, const bf16* __restrict__ zpad,
    int m0, int n0, bf16 (*Al)[64], bf16 (*Bl)[64])
{
  int t = threadIdx.x;
  int wv = t >> 6, lane = t & 63;
  int lr8 = lane >> 3, sseg = (lane & 7) ^ lr8;   // source 16B-seg (swizzled)
  int b = m0 >= PB ? 1 : 0;

  int ya[2], xa[2]; bool bv[2]; const bf16* wb[2];
  #pragma unroll
  for (int i = 0; i < 2; i++){
    int sp = (m0 - b*PB) + wv*16 + i*8 + lr8;
    ya[i] = sp / 48; xa[i] = sp % 48;
    int nrow = ncb + n0 + wv*16 + i*8 + lr8;
    bv[i] = nrow < N;
    wb[i] = W + (size_t)b*wbstride + (size_t)nrow*K + sseg*8;
  }

  int wm = (wv >> 1)*32, wn = (wv & 1)*32;
  int lrow = lane & 15, quad = lane >> 4;
  int sx = lrow & 7;
  int o0 = ((quad    ) ^ sx)*8;
  int o1 = ((quad + 4) ^ sx)*8;

  v4f acc00 = {0,0,0,0}, acc01 = {0,0,0,0}, acc10 = {0,0,0,0}, acc11 = {0,0,0,0};

  int dyx = 0, ic0 = 0;
  int ktn = K / 64;
  for (int kt = 0; kt < ktn; kt++){
    int dy = dyx/3 - 1, dx = dyx%3 - 1;
    #pragma unroll
    for (int i = 0; i < 2; i++){
      int ys = ya[i] + dy, xs = xa[i] + dx;
      const bf16* ga = (ys >= 0 && ys < 48 && xs >= 0 && xs < 48)
        ? Asrc + (size_t)(b*PB + ys*48 + xs)*AS + acol + ic0 + sseg*8 : zpad;
      gload_lds16(ga, &Al[wv*16 + i*8][0]);
      const bf16* gb = bv[i] ? wb[i] + kt*64 : zpad;
      gload_lds16(gb, &Bl[wv*16 + i*8][0]);
    }
    asm volatile("s_waitcnt vmcnt(0)" ::: "memory");
    __syncthreads();
    v8bf a00 = *reinterpret_cast<const v8bf*>(&Al[wm      + lrow][o0]);
    v8bf a10 = *reinterpret_cast<const v8bf*>(&Al[wm + 16 + lrow][o0]);
    v8bf a01 = *reinterpret_cast<const v8bf*>(&Al[wm      + lrow][o1]);
    v8bf a11 = *reinterpret_cast<const v8bf*>(&Al[wm + 16 + lrow][o1]);
    v8bf b00 = *reinterpret_cast<const v8bf*>(&Bl[wn      + lrow][o0]);
    v8bf b10 = *reinterpret_cast<const v8bf*>(&Bl[wn + 16 + lrow][o0]);
    v8bf b01 = *reinterpret_cast<const v8bf*>(&Bl[wn      + lrow][o1]);
    v8bf b11 = *reinterpret_cast<const v8bf*>(&Bl[wn + 16 + lrow][o1]);
    acc00 = __builtin_amdgcn_mfma_f32_16x16x32_bf16(a00, b00, acc00, 0, 0, 0);
    acc00 = __builtin_amdgcn_mfma_f32_16x16x32_bf16(a01, b01, acc00, 0, 0, 0);
    acc01 = __builtin_amdgcn_mfma_f32_16x16x32_bf16(a00, b10, acc01, 0, 0, 0);
    acc01 = __builtin_amdgcn_mfma_f32_16x16x32_bf16(a01, b11, acc01, 0, 0, 0);
    acc10 = __builtin_amdgcn_mfma_f32_16x16x32_bf16(a10, b00, acc10, 0, 0, 0);
    acc10 = __builtin_amdgcn_mfma_f32_16x16x32_bf16(a11, b01, acc10, 0, 0, 0);
    acc11 = __builtin_amdgcn_mfma_f32_16x16x32_bf16(a10, b10, acc11, 0, 0, 0);
    acc11 = __builtin_amdgcn_mfma_f32_16x16x32_bf16(a11, b11, acc11, 0, 0, 0);
    __syncthreads();
    ic0 += 64; if (ic0 == ICW){ ic0 = 0; dyx++; }
  }

  auto store_tile = [&](v4f a, int mi, int ni){
    int gcol = ncb + n0 + wn + ni*16 + lrow;
    if (gcol >= N) return;
    int sel = gcol / seg; sel = sel > 2 ? 2 : sel;
    const float* bp = sel == 0 ? bp0 : (sel == 1 ? bp1 : bp2);
    float bias = bp[gcol - sel*seg];
    int rowb = m0 + wm + mi*16 + quad*4;
    #pragma unroll
    for (int rg = 0; rg < 4; rg++){
      float v = a[rg] + bias;
      if (RELU) v = fmaxf(v, 0.f);
      if constexpr (sizeof(OT) == 2) out[(size_t)(rowb+rg)*ldo + (gcol - ncb)] = f2b(v);
      else                           out[(size_t)(rowb+rg)*ldo + (gcol - ncb)] = (OT)v;
    }
  };
  store_tile(acc00, 0, 0); store_tile(acc01, 0, 1);
  store_tile(acc10, 1, 0); store_tile(acc11, 1, 1);
}

template<bool RELU, typename OT>
__global__ __launch_bounds__(256) void k_gemm(
    const bf16* __restrict__ Asrc, int AS, int acol, int ICW,
    const bf16* __restrict__ W, int K, size_t wbstride,
    const float* __restrict__ bp0, const float* __restrict__ bp1, const float* __restrict__ bp2, int seg,
    OT* __restrict__ out, int N, int ncb, int ldo, const bf16* __restrict__ zpad)
{
  __shared__ __align__(16) bf16 Al[64][64];
  __shared__ __align__(16) bf16 Bl[64][64];
  gemm_body<RELU, OT>(Asrc, AS, acol, ICW, W, K, wbstride, bp0, bp1, bp2, seg,
                      out, N, ncb, ldo, zpad, blockIdx.x*64, blockIdx.y*64, Al, Bl);
}

// merged 3 small GEMMs: blockIdx.y selects {gamma1, beta1+gamma2, beta2+z0beta} config
__global__ __launch_bounds__(256) void k_gsmall(
    const bf16* __restrict__ HS, const bf16* __restrict__ WSMALL, const float* __restrict__ BCOL,
    float* __restrict__ GBS, const bf16* __restrict__ zpad)
{
  __shared__ __align__(16) bf16 Al[64][64];
  __shared__ __align__(16) bf16 Bl[64][64];
  int y = blockIdx.y;
  int acol = y == 0 ? 128 : (y == 1 ? 256 : 0);
  const bf16* W = WSMALL + (y == 0 ? 0 : (y == 1 ? 16*1152 : 48*1152));
  const float* bp = BCOL + (y == 0 ? 0 : (y == 1 ? 16 : 48));
  float* out = GBS + (y == 0 ? 0 : (y == 1 ? 16 : 48));
  int N = y == 1 ? 32 : 16;
  gemm_body<false, float>(HS, 384, acol, 128, W, 1152, 0, bp, bp, bp, 9999,
                          out, N, 0, 64, zpad, blockIdx.x*64, 0, Al, Bl);
}

// ---------- pure gamma GEMM: GAMMA[p][c] = im2col(HS)*WG0^T + bg0 ----------
__global__ __launch_bounds__(256, 4) void k_gg(
    const bf16* __restrict__ HS, const bf16* __restrict__ WG0, const float* __restrict__ BG0,
    bf16* __restrict__ GAMMA, const bf16* __restrict__ zpad)
{
  __shared__ __align__(16) bf16 Al[128][64];
  __shared__ __align__(16) bf16 Bl[128][64];
  int t = threadIdx.x;
  int m0 = blockIdx.x*128, n0 = blockIdx.y*128;
  int b = m0 >= PB ? 1 : 0;
  int wv = t >> 6, lane = t & 63;
  int lr8 = lane >> 3, sseg = (lane & 7) ^ lr8;
  int spbase = m0 - b*PB;

  int ya[4], xa[4];
  #pragma unroll
  for (int i = 0; i < 4; i++){
    int sp = spbase + wv*32 + i*8 + lr8;
    ya[i] = sp / 48; xa[i] = sp % 48;
  }
  const bf16* wgb = WG0 + (size_t)(n0 + wv*32 + lr8)*1152 + sseg*8;

  int wm = wv*32, lrow = lane & 15, quad = lane >> 4;
  int sx = lrow & 7;

  v4f acc[2][8];
  #pragma unroll
  for (int mi = 0; mi < 2; mi++)
    #pragma unroll
    for (int ni = 0; ni < 8; ni++) acc[mi][ni] = (v4f){0,0,0,0};

  for (int kt = 0; kt < 18; kt++){
    int dyx = kt >> 1, icr = (kt & 1) << 6;
    int dy = dyx/3 - 1, dx = dyx%3 - 1;
    #pragma unroll
    for (int i = 0; i < 4; i++){
      int ys = ya[i] + dy, xs = xa[i] + dx;
      const bf16* ga = (ys >= 0 && ys < 48 && xs >= 0 && xs < 48)
        ? HS + (size_t)(b*PB + ys*48 + xs)*384 + icr + sseg*8 : zpad;
      gload_lds16(ga, &Al[wv*32 + i*8][0]);
      gload_lds16(wgb + (size_t)(i*8)*1152 + dyx*128 + icr, &Bl[wv*32 + i*8][0]);
    }
    asm volatile("s_waitcnt vmcnt(0)" ::: "memory");
    __syncthreads();
    #pragma unroll
    for (int kh = 0; kh < 2; kh++){
      int oa = ((kh*4 + quad) ^ sx)*8;
      v8bf a0 = *reinterpret_cast<const v8bf*>(&Al[wm      + lrow][oa]);
      v8bf a1 = *reinterpret_cast<const v8bf*>(&Al[wm + 16 + lrow][oa]);
      #pragma unroll
      for (int ni = 0; ni < 8; ni++){
        v8bf bn = *reinterpret_cast<const v8bf*>(&Bl[ni*16 + lrow][oa]);
        acc[0][ni] = __builtin_amdgcn_mfma_f32_16x16x32_bf16(a0, bn, acc[0][ni], 0, 0, 0);
        acc[1][ni] = __builtin_amdgcn_mfma_f32_16x16x32_bf16(a1, bn, acc[1][ni], 0, 0, 0);
      }
    }
    __syncthreads();
  }

  #pragma unroll
  for (int mi = 0; mi < 2; mi++){
    int pr = m0 + wm + mi*16 + quad*4;
    #pragma unroll
    for (int ni = 0; ni < 8; ni++){
      int gc = n0 + ni*16 + lrow;
      float bg = BG0[gc];
      #pragma unroll
      for (int rg = 0; rg < 4; rg++)
        GAMMA[(size_t)(pr + rg)*3072 + gc] = f2b(acc[mi][ni][rg] + bg);
    }
  }
}

// ---------- z0 contraction v2: z0[p,oc] += sum_c xn[p,c]*(1+gamma[p,c])*w0[oc,c] ----------
__global__ __launch_bounds__(256) void k_zc(
    const void* __restrict__ x, const bf16* __restrict__ GAMMA, const int* __restrict__ flag,
    const float* __restrict__ stats, const float* __restrict__ w0f, float* __restrict__ z0)
{
  __shared__ bf16 gmT[64][130];     // [c][px] 64c x 128px; word-stride 65 (odd) -> conflict-free
  __shared__ float w0l[8][128];
  __shared__ float red[4][128][9];  // pad 9 -> 4-way max on writes
  int t = threadIdx.x;
  int p0 = blockIdx.x*128, cb = blockIdx.y;
  int b = p0 / PB;
  int spbase = p0 - b*PB;
  int fl = *flag;
  float mean = stats[b*2], rstd = stats[b*2+1];
  int lane = t & 63, cg = t >> 6;
  int c0b = cb*128;

  for (int i = t; i < 1024; i += 256) w0l[i >> 7][i & 127] = w0f[(size_t)(i >> 7)*3072 + c0b + (i & 127)];

  float acc0[8], acc1[8];
  #pragma unroll
  for (int oc = 0; oc < 8; oc++){ acc0[oc] = 0.f; acc1[oc] = 0.f; }

  for (int ct = 0; ct < 2; ct++){
    int c0 = c0b + ct*64;
    {
      int cl = t & 63, pr = t >> 6;
      #pragma unroll
      for (int k = 0; k < 32; k++){
        int p = pr + k*4;
        gmT[cl][p] = GAMMA[(size_t)(p0 + p)*3072 + c0 + cl];
      }
    }
    __syncthreads();
    #pragma unroll
    for (int ci = 0; ci < 16; ci++){
      int c = cg*16 + ci;
      float xv0, xv1;
      if (fl){
        const float* xp = (const float*)x + ((size_t)(b*3072 + c0 + c))*2304 + spbase + lane*2;
        float2 v = *reinterpret_cast<const float2*>(xp);
        xv0 = v.x; xv1 = v.y;
      } else {
        const bf16* xp = (const bf16*)x + ((size_t)(b*3072 + c0 + c))*2304 + spbase + lane*2;
        xv0 = b2f(xp[0]); xv1 = b2f(xp[1]);
      }
      float t0 = (xv0 - mean)*rstd*(1.f + b2f(gmT[c][lane*2]));
      float t1 = (xv1 - mean)*rstd*(1.f + b2f(gmT[c][lane*2 + 1]));
      #pragma unroll
      for (int oc = 0; oc < 8; oc++){
        float wv = w0l[oc][ct*64 + c];
        acc0[oc] += t0*wv; acc1[oc] += t1*wv;
      }
    }
    __syncthreads();
  }
  #pragma unroll
  for (int oc = 0; oc < 8; oc++){
    red[cg][lane*2    ][oc] = acc0[oc];
    red[cg][lane*2 + 1][oc] = acc1[oc];
  }
  __syncthreads();
  #pragma unroll
  for (int j = 0; j < 4; j++){
    int idx = t + j*256;          // 1024 = 128 px * 8 oc
    int p2 = idx >> 3, o2 = idx & 7;
    float s = red[0][p2][o2] + red[1][p2][o2] + red[2][p2][o2] + red[3][p2][o2];
    atomicAdd(&z0[(size_t)(p0 + p2)*8 + o2], s);
  }
}

// ---------- z0 init: bias0 + beta-contraction (GBS cols 48..55 hi + 56..63 lo) ----------
__global__ __launch_bounds__(256) void k_z0init(const float* __restrict__ b0f, const float* __restrict__ GBS,
                                                float* __restrict__ z0){
  int i = blockIdx.x*256 + threadIdx.x;
  if (i >= 36864) return;
  int p = i >> 3, oc = i & 7;
  z0[i] = b0f[oc] + GBS[(size_t)p*64 + 48 + oc] + GBS[(size_t)p*64 + 56 + oc];
}

__global__ __launch_bounds__(256) void k_F1(const float* __restrict__ z0, const float* __restrict__ GBS,
    const float* __restrict__ stats, const float* __restrict__ w1f, const float* __restrict__ b1f,
    float* __restrict__ z1){
  int p = blockIdx.x*256 + threadIdx.x;
  if (p >= PTOT) return;
  int b = p / PB;
  float mean = stats[b*2], rstd = stats[b*2+1];
  const float* zr = z0 + (size_t)p*8;
  const float* gr = GBS + (size_t)p*64;
  float yv[8];
  #pragma unroll
  for (int c = 0; c < 8; c++) yv[c] = (zr[c] - mean)*rstd*(1.f + gr[c]) + gr[8 + c];
  #pragma unroll
  for (int oc = 0; oc < 16; oc++){
    float s = b1f[oc];
    #pragma unroll
    for (int c = 0; c < 8; c++) s += yv[c]*w1f[oc*8 + c];
    z1[(size_t)p*16 + oc] = softplus_f(s);
  }
}

__global__ __launch_bounds__(256) void k_F2(const float* __restrict__ z1, const float* __restrict__ GBS,
    const float* __restrict__ stats, const float* __restrict__ w2f, const float* __restrict__ b2f,
    void* __restrict__ outp, const int* __restrict__ flag){
  int p = blockIdx.x*256 + threadIdx.x;
  if (p >= PTOT) return;
  int b = p / PB;
  float mean = stats[b*2], rstd = stats[b*2+1];
  const float* zr = z1 + (size_t)p*16;
  const float* gr = GBS + (size_t)p*64 + 16;
  float s = b2f[0];
  #pragma unroll
  for (int c = 0; c < 16; c++){
    float yv = (zr[c] - mean)*rstd*(1.f + gr[c]) + gr[16 + c];
    s += yv*w2f[c];
  }
  float r = softplus_f(s);
  if (*flag) ((float*)outp)[p] = r;
  else       ((bf16*)outp)[p] = f2b(r);
}

extern "C" void kernel_launch(void* const* d_in, const int* in_sizes, int n_in,
                              void* d_out, int out_size, void* d_ws, size_t ws_size,
                              hipStream_t stream){
  const void* x_main = d_in[0];
  const void* f_sem  = d_in[1];
  const int*  segmap = (const int*)d_in[2];

  char* ws = (char*)d_ws;
  size_t o = 0;
  auto alloc = [&](size_t bytes){ size_t r = o; o = (o + bytes + 255) & ~(size_t)255; return r; };
  float* MEANS = (float*)(ws + alloc(98304u*4));
  bf16*  AHL   = (bf16*) (ws + alloc(589824u*2));    // PTOT*128 hi/lo A weights
  bf16*  WTT   = (bf16*) (ws + alloc(884736u*2));    // 2*384*1152 folded conv weights
  float* TTACC = (float*)(ws + alloc(442368u*4));    // f32 TT accumulator
  bf16*  WG0   = (bf16*) (ws + alloc(3538944u*2));
  bf16*  WSMALL= (bf16*) (ws + alloc(73728u*2));
  bf16*  HS    = (bf16*) (ws + alloc(1769472u*2));
  float* WSP   = (float*)(ws + alloc(2654208u*4));   // 384*6912 permuted ws (f32)
  bf16*  GAMMA = (bf16*) (ws + alloc(14155776u*2));  // 4608*3072 gamma (layer 0)
  float* GBS   = (float*)(ws + alloc(294912u*4));
  float* Z0    = (float*)(ws + alloc(36864u*4));
  float* Z1    = (float*)(ws + alloc(73728u*4));
  float2* LNP  = (float2*)(ws + alloc(256u*8));
  float* STATS = (float*)(ws + alloc(16u*4));
  int*   FLAG  = (int*)  (ws + alloc(64u));
  float* SMALLF= (float*)(ws + alloc(31321u*4));
  float* MB    = (float*)(ws + alloc(9216u*4));
  float* BCOL  = (float*)(ws + alloc(64u*4));
  bf16*  ZPAD  = (bf16*) (ws + alloc(512u));

  float *BS0=SMALLF+0, *BS1=SMALLF+128, *BS2=SMALLF+256;
  float *BG0=SMALLF+384;
  float *W0=SMALLF+6576, *B0=SMALLF+31152;
  float *W1=SMALLF+31160, *B1=SMALLF+31288;
  float *W2=SMALLF+31304, *B2=SMALLF+31320;

  k_sniff<<<1, 256, 0, stream>>>((const unsigned*)x_main, FLAG, (float*)ZPAD);
  k_cvt_small<<<1887, 256, 0, stream>>>(d_in[4], d_in[10], d_in[16], d_in[6], d_in[8],
      d_in[12], d_in[14], d_in[18], d_in[20], d_in[21], d_in[22], d_in[23], d_in[24],
      d_in[25], d_in[26], SMALLF, FLAG, MB, TTACC);
  k_bcol<<<1, 256, 0, stream>>>(SMALLF, BCOL);
  k_mbeta<<<dim3(18,24), 256, 0, stream>>>(d_in[7], FLAG, W0, MB);
  k_wsm<<<36, 256, 0, stream>>>(MB, WSMALL);

  k_permoc<<<768, 256, 0, stream>>>(d_in[5], WG0, FLAG);          // coalesced WG0 permute
  k_permws<<<384, 256, 0, stream>>>(d_in[3], d_in[9], d_in[15], FLAG, WSP);
  k_permW4<<<216, 256, 0, stream>>>(d_in[11], d_in[13], d_in[17], d_in[19], WSMALL, FLAG);

  k_ln_partial<<<dim3(128,2), 256, 0, stream>>>(x_main, FLAG, LNP);
  k_ln_final<<<2, 128, 0, stream>>>(LNP, STATS);
  k_seg_means<<<dim3(64,2), 256, 0, stream>>>(f_sem, FLAG, segmap, MEANS);
  k_tt<<<dim3(216,2,3), 256, 0, stream>>>(WSP, MEANS, TTACC);
  k_wtt<<<1728, 256, 0, stream>>>(TTACC, WTT);
  k_A<<<PTOT, 192, 0, stream>>>(segmap, AHL);

  // G1: h = relu(conv3x3(sem, ws_l)) for all 3 layers -> HS (4608,384), folded-weight K=1152
  k_gemm<true, bf16><<<dim3(72,6), 256, 0, stream>>>(AHL, 128, 0, 128, WTT, 1152, (size_t)384*1152,
      BS0, BS1, BS2, 128, HS, 384, 0, 384, ZPAD);
  // merged small GEMMs (gamma1/beta1/gamma2/beta2/z0beta)
  k_gsmall<<<dim3(72,3), 256, 0, stream>>>(HS, WSMALL, BCOL, GBS, ZPAD);

  // layer-0 split: gamma GEMM -> GAMMA, then streaming z0 contraction
  k_z0init<<<144, 256, 0, stream>>>(B0, GBS, Z0);
  k_gg<<<dim3(36,24), 256, 0, stream>>>(HS, WG0, BG0, GAMMA, ZPAD);
  k_zc<<<dim3(36,24), 256, 0, stream>>>(x_main, GAMMA, FLAG, STATS, W0, Z0);
  k_spln<<<2, 256, 0, stream>>>(Z0, 18432, STATS + 4);

  k_F1<<<18, 256, 0, stream>>>(Z0, GBS, STATS + 4, W1, B1, Z1);
  k_ln_small<<<2, 256, 0, stream>>>(Z1, 36864, STATS + 8);
  k_F2<<<18, 256, 0, stream>>>(Z1, GBS, STATS + 8, W2, B2, d_out, FLAG);
}